// Round 1
// 5008.541 us; speedup vs baseline: 1.0220x; 1.0220x over previous
//
#include <hip/hip_runtime.h>
#include <hip/hip_bf16.h>
#include <math.h>

#define BIGF 1e4f

typedef __attribute__((ext_vector_type(8))) short bf16x8;
typedef __attribute__((ext_vector_type(4))) float f32x4;

__device__ __forceinline__ unsigned short f2bf_rne(float v) {
    unsigned u = __float_as_uint(v);
    return (unsigned short)((u + 0x7FFFu + ((u >> 16) & 1u)) >> 16);
}
__device__ __forceinline__ void split_bf16(float v, unsigned short& h, unsigned short& l) {
    unsigned u = __float_as_uint(v);
    unsigned hr = (u + 0x7FFFu + ((u >> 16) & 1u)) >> 16;
    h = (unsigned short)hr;
    float hf = __uint_as_float(hr << 16);
    l = f2bf_rne(v - hf);
}

// async global->LDS, 16B per lane, wave-uniform LDS base + lane*16
__device__ __forceinline__ void gl16(const unsigned short* g, unsigned short* l) {
    __builtin_amdgcn_global_load_lds(
        (const __attribute__((address_space(1))) unsigned int*)g,
        (__attribute__((address_space(3))) unsigned int*)l, 16, 0, 0);
}

// ---------------- EDT row pass ----------------------------------------------
__global__ __launch_bounds__(64)
void edt_rows_k(const float* __restrict__ logits, const int* __restrict__ truem,
                float* __restrict__ g2o, float* __restrict__ g2z)
{
    int blk = blockIdx.x;
    int a = blk / 384, row = blk % 384;
    int lane = threadIdx.x;
    int j0 = lane * 6;
    float mk[6];
    if (a < 2) {
        const float* l0 = logits + (size_t)a * 2 * 147456 + (size_t)row * 384;
        const float* l1 = l0 + 147456;
        #pragma unroll
        for (int u = 0; u < 6; ++u) mk[u] = (l1[j0+u] > l0[j0+u]) ? 1.f : 0.f;
    } else {
        const int* t = truem + (size_t)(a - 2) * 147456 + (size_t)row * 384;
        #pragma unroll
        for (int u = 0; u < 6; ++u) mk[u] = (t[j0+u] != 0) ? 1.f : 0.f;
    }
    float lo[6], lz[6], ro[6], rz[6];
    float run_lo = -BIGF, run_lz = -BIGF;
    #pragma unroll
    for (int u = 0; u < 6; ++u) {
        float jf = (float)(j0 + u);
        if (mk[u] > 0.5f) run_lo = jf; else run_lz = jf;
        lo[u] = run_lo; lz[u] = run_lz;
    }
    float inc_o = run_lo, inc_z = run_lz;
    for (int off = 1; off < 64; off <<= 1) {
        float to = __shfl_up(inc_o, off), tz = __shfl_up(inc_z, off);
        if (lane >= off) { inc_o = fmaxf(inc_o, to); inc_z = fmaxf(inc_z, tz); }
    }
    float ex_o = __shfl_up(inc_o, 1); if (lane == 0) ex_o = -BIGF;
    float ex_z = __shfl_up(inc_z, 1); if (lane == 0) ex_z = -BIGF;

    float run_ro = BIGF, run_rz = BIGF;
    #pragma unroll
    for (int u = 5; u >= 0; --u) {
        float jf = (float)(j0 + u);
        if (mk[u] > 0.5f) run_ro = jf; else run_rz = jf;
        ro[u] = run_ro; rz[u] = run_rz;
    }
    float in2_o = run_ro, in2_z = run_rz;
    for (int off = 1; off < 64; off <<= 1) {
        float to = __shfl_down(in2_o, off), tz = __shfl_down(in2_z, off);
        if (lane + off < 64) { in2_o = fminf(in2_o, to); in2_z = fminf(in2_z, tz); }
    }
    float sx_o = __shfl_down(in2_o, 1); if (lane == 63) sx_o = BIGF;
    float sx_z = __shfl_down(in2_z, 1); if (lane == 63) sx_z = BIGF;

    size_t ob = (size_t)a * 147456 + (size_t)row * 384;
    #pragma unroll
    for (int u = 0; u < 6; ++u) {
        float jf = (float)(j0 + u);
        float dlo = jf - fmaxf(lo[u], ex_o);
        float dro = fminf(ro[u], sx_o) - jf;
        float go = fminf(fminf(dlo, dro), BIGF);
        float dlz = jf - fmaxf(lz[u], ex_z);
        float drz = fminf(rz[u], sx_z) - jf;
        float gz = fminf(fminf(dlz, drz), BIGF);
        g2o[ob + j0 + u] = go * go;
        g2z[ob + j0 + u] = gz * gz;
    }
}

// ---------------- EDT column pass -------------------------------------------
__global__ __launch_bounds__(256)
void edt_cols_k(const float* __restrict__ g2o, const float* __restrict__ g2z,
                float* __restrict__ sdm)
{
    int a = blockIdx.y;
    int w0 = blockIdx.x * 8;
    __shared__ float so[384][8];
    __shared__ float sz[384][8];
    int tid = threadIdx.x;
    for (int h = 0; h < 12; ++h) {
        int lin = tid + 256 * h;
        int ip = lin >> 3, ww = lin & 7;
        so[ip][ww] = g2o[(size_t)a * 147456 + (size_t)ip * 384 + w0 + ww];
        sz[ip][ww] = g2z[(size_t)a * 147456 + (size_t)ip * 384 + w0 + ww];
    }
    __syncthreads();
    int w = tid & 7, ib = tid >> 3;
    float vo[12], vz[12];
    #pragma unroll
    for (int r = 0; r < 12; ++r) { vo[r] = 3.4e38f; vz[r] = 3.4e38f; }
    for (int ip = 0; ip < 384; ++ip) {
        float go = so[ip][w], gz = sz[ip][w];
        #pragma unroll
        for (int r = 0; r < 12; ++r) {
            float d = (float)(ib + 32 * r - ip);
            float dd = d * d;
            vo[r] = fminf(vo[r], dd + go);
            vz[r] = fminf(vz[r], dd + gz);
        }
    }
    #pragma unroll
    for (int r = 0; r < 12; ++r) {
        sdm[(size_t)a * 147456 + (size_t)(ib + 32 * r) * 384 + w0 + w] =
            sqrtf(vo[r]) - sqrtf(vz[r]);
    }
}

// ---------------- channel-reduced patch weight ------------------------------
__global__ void weff_k(const float* __restrict__ pw, float* __restrict__ W)
{
    int i = blockIdx.x * 256 + threadIdx.x;
    if (i < 196608) W[i] = pw[i] + pw[i + 196608] + pw[i + 393216];
}

// ---------------- generic transpose + split: [K,N] f32 -> [N,K] bf16 h/l ----
__global__ __launch_bounds__(256)
void tconv_k(const float* __restrict__ src, unsigned short* __restrict__ dh,
             unsigned short* __restrict__ dl, int K, int N)
{
    __shared__ float tile[32][33];
    int t = blockIdx.x;
    int ntk = K >> 5;
    int tn = t / ntk, tk = t % ntk;
    int tid = threadIdx.x;
    int tx = tid & 31, ty = tid >> 5;
    #pragma unroll
    for (int i = 0; i < 4; ++i) {
        int k = tk * 32 + ty + i * 8;
        tile[ty + i * 8][tx] = src[(size_t)k * N + tn * 32 + tx];
    }
    __syncthreads();
    #pragma unroll
    for (int i = 0; i < 4; ++i) {
        int n = tn * 32 + ty + i * 8;
        float v = tile[tx][ty + i * 8];
        unsigned short h, l;
        split_bf16(v, h, l);
        dh[(size_t)n * K + tk * 32 + tx] = h;
        dl[(size_t)n * K + tk * 32 + tx] = l;
    }
}

// ---------------- fused per-layer weight transpose+split --------------------
__global__ __launch_bounds__(256)
void wconv_layer_k(const float* __restrict__ qkv, const float* __restrict__ proj,
                   const float* __restrict__ fc1, const float* __restrict__ fc2,
                   unsigned short* qkvTh, unsigned short* qkvTl,
                   unsigned short* projTh, unsigned short* projTl,
                   unsigned short* fc1Th, unsigned short* fc1Tl,
                   unsigned short* fc2Th, unsigned short* fc2Tl)
{
    __shared__ float tile[32][33];
    int t = blockIdx.x;
    const float* src; unsigned short *dh, *dl; int K, N, tt;
    if (t < 1728)      { src = qkv;  dh = qkvTh;  dl = qkvTl;  K = 768;  N = 2304; tt = t; }
    else if (t < 2304) { src = proj; dh = projTh; dl = projTl; K = 768;  N = 768;  tt = t - 1728; }
    else if (t < 4608) { src = fc1;  dh = fc1Th;  dl = fc1Tl;  K = 768;  N = 3072; tt = t - 2304; }
    else               { src = fc2;  dh = fc2Th;  dl = fc2Tl;  K = 3072; N = 768;  tt = t - 4608; }
    int ntk = K >> 5;
    int tn = tt / ntk, tk = tt % ntk;
    int tid = threadIdx.x;
    int tx = tid & 31, ty = tid >> 5;
    #pragma unroll
    for (int i = 0; i < 4; ++i) {
        int k = tk * 32 + ty + i * 8;
        tile[ty + i * 8][tx] = src[(size_t)k * N + tn * 32 + tx];
    }
    __syncthreads();
    #pragma unroll
    for (int i = 0; i < 4; ++i) {
        int n = tn * 32 + ty + i * 8;
        float v = tile[tx][ty + i * 8];
        unsigned short h, l;
        split_bf16(v, h, l);
        dh[(size_t)n * K + tk * 32 + tx] = h;
        dl[(size_t)n * K + tk * 32 + tx] = l;
    }
}

// ---------------- gather patch vectors, split -------------------------------
__global__ void pvec_split_k(const float* __restrict__ sdm,
                             unsigned short* __restrict__ ph,
                             unsigned short* __restrict__ pl)
{
    int idx = blockIdx.x * 256 + threadIdx.x;   // 589824 total
    int cc = idx & 15, r = (idx >> 4) & 15, p = idx >> 8;
    int px = p % 24, py = (p / 24) % 24, aa = p / 576;
    float v = sdm[(size_t)aa * 147456 + (size_t)(py * 16 + r) * 384 + px * 16 + cc];
    unsigned short h, l;
    split_bf16(v, h, l);
    ph[idx] = h; pl[idx] = l;
}

// ---------------- cls + pos assembly ---------------------------------------
__global__ void addpos_k(const float* __restrict__ tok, const float* __restrict__ cls,
                         const float* __restrict__ pos, float* __restrict__ X)
{
    int idx = blockIdx.x * 256 + threadIdx.x;
    if (idx >= 1772544) return;
    int d = idx % 768;
    int t = (idx / 768) % 577;
    int img = idx / (768 * 577);
    float v;
    if (t == 0) v = cls[d] + pos[d];
    else v = tok[((size_t)img * 576 + (t - 1)) * 768 + d] + pos[(size_t)t * 768 + d];
    X[idx] = v;
}

// ---------------- LayerNorm -> split bf16 -----------------------------------
__global__ __launch_bounds__(256)
void ln_split_k(const float* __restrict__ X, const float* __restrict__ g,
                const float* __restrict__ b, unsigned short* __restrict__ Yh,
                unsigned short* __restrict__ Yl)
{
    int row = blockIdx.x;
    const float* x = X + (size_t)row * 768;
    int tid = threadIdx.x;
    __shared__ float rs[4], rss[4];
    float v0 = x[tid], v1 = x[tid + 256], v2 = x[tid + 512];
    float s = v0 + v1 + v2;
    float ss = v0 * v0 + v1 * v1 + v2 * v2;
    for (int off = 32; off; off >>= 1) {
        s  += __shfl_xor(s, off, 64);
        ss += __shfl_xor(ss, off, 64);
    }
    if ((tid & 63) == 0) { rs[tid >> 6] = s; rss[tid >> 6] = ss; }
    __syncthreads();
    s  = rs[0] + rs[1] + rs[2] + rs[3];
    ss = rss[0] + rss[1] + rss[2] + rss[3];
    float mu  = s * (1.f / 768.f);
    float var = ss * (1.f / 768.f) - mu * mu;
    float inv = rsqrtf(var + 1e-6f);
    unsigned short h, l;
    float y0 = (v0 - mu) * inv * g[tid]       + b[tid];
    float y1 = (v1 - mu) * inv * g[tid + 256] + b[tid + 256];
    float y2 = (v2 - mu) * inv * g[tid + 512] + b[tid + 512];
    size_t base = (size_t)row * 768;
    split_bf16(y0, h, l); Yh[base + tid]       = h; Yl[base + tid]       = l;
    split_bf16(y1, h, l); Yh[base + tid + 256] = h; Yl[base + tid + 256] = l;
    split_bf16(y2, h, l); Yh[base + tid + 512] = h; Yl[base + tid + 512] = l;
}

// ---------------- split-bf16 MFMA GEMM (m97 structure) ----------------------
// A: Ah/Al [M,K] bf16 row-major (M padded to 128-mult in memory)
// B: Bh/Bl [N,K] bf16 row-major (pre-transposed weights)
// OP: 0 = store fp32 Cf, 1 = gelu -> split bf16 Ch/Cl, 2 = fp32 residual Cf=acc+bias+R
template<int OP>
__global__ __launch_bounds__(256, 2)
void gemm_bt_k(const unsigned short* __restrict__ Ah_g, const unsigned short* __restrict__ Al_g,
               const unsigned short* __restrict__ Bh_g, const unsigned short* __restrict__ Bl_g,
               const float* __restrict__ bias, const float* __restrict__ R,
               float* __restrict__ Cf, unsigned short* __restrict__ Ch,
               unsigned short* __restrict__ Cl, int M, int N, int K)
{
    __shared__ unsigned short Ah[128 * 32];
    __shared__ unsigned short Al[128 * 32];
    __shared__ unsigned short Bh[128 * 32];
    __shared__ unsigned short Bl[128 * 32];

    int tid = threadIdx.x;
    int lane = tid & 63, wave = tid >> 6;
    int bn = blockIdx.x * 128, bm = blockIdx.y * 128;
    int ln = lane & 15, quad = lane >> 4;
    int wm = (wave >> 1) * 64, wn = (wave & 1) * 64;

    // staging: each wave stages rows [wave*32, wave*32+32) of each tile,
    // 16 rows per global_load_lds (64 lanes x 16B = 1KB = 16 rows x 64B)
    int srow = wave * 32 + (lane >> 2);
    int scol = (lane & 3) * 8;
    const unsigned short* pAh = Ah_g + (size_t)(bm + srow) * K + scol;
    const unsigned short* pAl = Al_g + (size_t)(bm + srow) * K + scol;
    const unsigned short* pBh = Bh_g + (size_t)(bn + srow) * K + scol;
    const unsigned short* pBl = Bl_g + (size_t)(bn + srow) * K + scol;
    unsigned short* dA0 = Ah + wave * 1024;
    unsigned short* dA1 = Al + wave * 1024;
    unsigned short* dB0 = Bh + wave * 1024;
    unsigned short* dB1 = Bl + wave * 1024;
    size_t rstep = (size_t)16 * K;

    f32x4 acc[4][4] = {};

    for (int k0 = 0; k0 < K; k0 += 32) {
        gl16(pAh + k0,         dA0);
        gl16(pAh + k0 + rstep, dA0 + 512);
        gl16(pAl + k0,         dA1);
        gl16(pAl + k0 + rstep, dA1 + 512);
        gl16(pBh + k0,         dB0);
        gl16(pBh + k0 + rstep, dB0 + 512);
        gl16(pBl + k0,         dB1);
        gl16(pBl + k0 + rstep, dB1 + 512);
        __syncthreads();

        bf16x8 fbh[4], fbl[4];
        #pragma unroll
        for (int nt = 0; nt < 4; ++nt) {
            fbh[nt] = *(const bf16x8*)&Bh[(wn + nt * 16 + ln) * 32 + quad * 8];
            fbl[nt] = *(const bf16x8*)&Bl[(wn + nt * 16 + ln) * 32 + quad * 8];
        }
        #pragma unroll
        for (int mt = 0; mt < 4; ++mt) {
            bf16x8 fah = *(const bf16x8*)&Ah[(wm + mt * 16 + ln) * 32 + quad * 8];
            bf16x8 fal = *(const bf16x8*)&Al[(wm + mt * 16 + ln) * 32 + quad * 8];
            #pragma unroll
            for (int nt = 0; nt < 4; ++nt) {
                acc[mt][nt] = __builtin_amdgcn_mfma_f32_16x16x32_bf16(fah, fbh[nt], acc[mt][nt], 0, 0, 0);
                acc[mt][nt] = __builtin_amdgcn_mfma_f32_16x16x32_bf16(fah, fbl[nt], acc[mt][nt], 0, 0, 0);
                acc[mt][nt] = __builtin_amdgcn_mfma_f32_16x16x32_bf16(fal, fbh[nt], acc[mt][nt], 0, 0, 0);
            }
        }
        __syncthreads();
    }

    // epilogue: D row = quad*4 + i, col = ln
    #pragma unroll
    for (int mt = 0; mt < 4; ++mt) {
        #pragma unroll
        for (int i = 0; i < 4; ++i) {
            int r = bm + wm + mt * 16 + quad * 4 + i;
            if (r >= M) continue;
            #pragma unroll
            for (int nt = 0; nt < 4; ++nt) {
                int c = bn + wn + nt * 16 + ln;
                float v = acc[mt][nt][i] + bias[c];
                if (OP == 0) {
                    Cf[(size_t)r * N + c] = v;
                } else if (OP == 1) {
                    v = 0.5f * v * (1.f + erff(v * 0.70710678118654752f));
                    unsigned short h, l;
                    split_bf16(v, h, l);
                    Ch[(size_t)r * N + c] = h;
                    Cl[(size_t)r * N + c] = l;
                } else {
                    Cf[(size_t)r * N + c] = v + R[(size_t)r * N + c];
                }
            }
        }
    }
}

// ---------------- MFMA flash attention (split-bf16) -------------------------
// 4 waves/block, 16 queries/wave (64 q/block). K/V streamed in 64-token tiles.
// All LDS tiles [rows][64] bf16 with XOR swizzle elem ^= (row&7)<<3:
//   keeps ds_read_b128 16B-aligned + bank-schedulable (G4 fix for 128B rows).
// Fragment layouts identical to gemm_bt_k (A/B row = lane&15, k = quad*8;
// C/D row = quad*4+i, col = lane&15). 3-term split product (hh+hl+lh).
__global__ __launch_bounds__(256)
void attn_k(const float* __restrict__ QKV, unsigned short* __restrict__ Oh,
            unsigned short* __restrict__ Ol)
{
    const int T = 577;
    int img = blockIdx.z, head = blockIdx.y;
    int q0 = blockIdx.x * 64;
    const float* base = QKV + (size_t)img * T * 2304;

    __shared__ unsigned short Ksh[64 * 64], Ksl[64 * 64];   // K  [tok][d]
    __shared__ unsigned short Vth[64 * 64], Vtl[64 * 64];   // V^T [d][tok]
    __shared__ unsigned short Psh[4][16 * 64], Psl[4][16 * 64]; // per-wave P [q][tok]

    int tid = threadIdx.x;
    int wave = tid >> 6, lane = tid & 63;
    int ln = lane & 15, quad = lane >> 4;

    // ---- Q fragments: A-frag row q = ln, d = kk*32 + quad*8 (x0.125) ----
    bf16x8 qh[2], qlo[2];
    {
        int qtok = q0 + wave * 16 + ln;
        const float* qp = base + (size_t)qtok * 2304 + head * 64 + quad * 8;
        #pragma unroll
        for (int kk = 0; kk < 2; ++kk) {
            #pragma unroll
            for (int u = 0; u < 8; ++u) {
                float v = 0.f;
                if (qtok < T) v = qp[kk * 32 + u] * 0.125f;
                unsigned short h, l;
                split_bf16(v, h, l);
                qh[kk][u] = (short)h; qlo[kk][u] = (short)l;
            }
        }
    }

    float m[4], lsum[4];
    f32x4 acc_o[4] = {};          // O: row q = quad*4+i, col d = nt*16+ln
    #pragma unroll
    for (int i = 0; i < 4; ++i) { m[i] = -1e30f; lsum[i] = 0.f; }

    int kd  = lane;               // K staging: lane = d
    int vr0 = (tid >> 3) * 2;     // V staging: token pair
    int vdc = tid & 7;            // V staging: d column base

    for (int c0 = 0; c0 < T; c0 += 64) {
        // ---- stage K [tok][d]: each wave does rows wave*16..+15, lane = d.
        // Pack (d,d+1) via shfl: even lanes write Kh pair, odd write Kl pair
        // (32 active lanes -> 32 distinct banks: conflict-free).
        #pragma unroll
        for (int it = 0; it < 16; ++it) {
            int r = wave * 16 + it;
            float v = 0.f;
            if (c0 + r < T) v = base[(size_t)(c0 + r) * 2304 + 768 + head * 64 + kd];
            unsigned short h, l;
            split_bf16(v, h, l);
            unsigned hx = (unsigned)__shfl_xor((int)h, 1);
            unsigned lx = (unsigned)__shfl_xor((int)l, 1);
            int e = (r * 64 + (kd & ~1)) ^ ((r & 7) << 3);
            if ((kd & 1) == 0) *(unsigned*)&Ksh[e] = (unsigned)h | (hx << 16);
            else               *(unsigned*)&Ksl[e] = lx | ((unsigned)l << 16);
        }
        // ---- stage V^T [d][tok]: thread owns token pair (vr0,vr0+1) x 8 d.
        // Row-pair packs locally into u32 (<=2-way banks with the swizzle).
        {
            const float* vp0 = base + (size_t)(c0 + vr0) * 2304 + 1536 + head * 64 + vdc;
            bool ok0 = (c0 + vr0) < T, ok1 = (c0 + vr0 + 1) < T;
            #pragma unroll
            for (int u = 0; u < 8; ++u) {
                float a = 0.f, b = 0.f;
                if (ok0) a = vp0[8 * u];
                if (ok1) b = vp0[2304 + 8 * u];
                unsigned short ha, la, hb, lb;
                split_bf16(a, ha, la);
                split_bf16(b, hb, lb);
                int d = vdc + 8 * u;
                int e = (d * 64 + vr0) ^ ((d & 7) << 3);
                *(unsigned*)&Vth[e] = (unsigned)ha | ((unsigned)hb << 16);
                *(unsigned*)&Vtl[e] = (unsigned)la | ((unsigned)lb << 16);
            }
        }
        __syncthreads();

        // ---- S = Q K^T (split 3-term) ----
        f32x4 s4[4] = {};
        #pragma unroll
        for (int nt = 0; nt < 4; ++nt) {
            int row = nt * 16 + ln;
            #pragma unroll
            for (int kk = 0; kk < 2; ++kk) {
                int e = (row * 64 + kk * 32 + quad * 8) ^ ((ln & 7) << 3);
                bf16x8 kbh = *(const bf16x8*)&Ksh[e];
                bf16x8 kbl = *(const bf16x8*)&Ksl[e];
                s4[nt] = __builtin_amdgcn_mfma_f32_16x16x32_bf16(qh[kk],  kbh, s4[nt], 0, 0, 0);
                s4[nt] = __builtin_amdgcn_mfma_f32_16x16x32_bf16(qh[kk],  kbl, s4[nt], 0, 0, 0);
                s4[nt] = __builtin_amdgcn_mfma_f32_16x16x32_bf16(qlo[kk], kbh, s4[nt], 0, 0, 0);
            }
        }

        // ---- online softmax: rows q = quad*4+i; cols spread over ln + nt.
        // Row reduce = local over nt + shfl_xor 1/2/4/8 (stays in quad group).
        bool full = (c0 + 64 <= T);
        float p[4][4];
        #pragma unroll
        for (int i = 0; i < 4; ++i) {
            float mx = -1e30f;
            #pragma unroll
            for (int nt = 0; nt < 4; ++nt) {
                float sv = s4[nt][i];
                if (!full && (c0 + nt * 16 + ln >= T)) sv = -1e30f;
                p[nt][i] = sv;
                mx = fmaxf(mx, sv);
            }
            mx = fmaxf(mx, __shfl_xor(mx, 1));
            mx = fmaxf(mx, __shfl_xor(mx, 2));
            mx = fmaxf(mx, __shfl_xor(mx, 4));
            mx = fmaxf(mx, __shfl_xor(mx, 8));
            float mnew = fmaxf(m[i], mx);
            float alpha = __expf(m[i] - mnew);
            m[i] = mnew;
            float rsum = 0.f;
            #pragma unroll
            for (int nt = 0; nt < 4; ++nt) {
                float pv = __expf(p[nt][i] - mnew);
                p[nt][i] = pv;
                rsum += pv;
            }
            rsum += __shfl_xor(rsum, 1); rsum += __shfl_xor(rsum, 2);
            rsum += __shfl_xor(rsum, 4); rsum += __shfl_xor(rsum, 8);
            lsum[i] = lsum[i] * alpha + rsum;
            acc_o[0][i] *= alpha; acc_o[1][i] *= alpha;
            acc_o[2][i] *= alpha; acc_o[3][i] *= alpha;
        }

        // ---- P -> split bf16 into per-wave LDS tile (C-layout write) ----
        unsigned short* php = Psh[wave];
        unsigned short* plp = Psl[wave];
        #pragma unroll
        for (int i = 0; i < 4; ++i) {
            int row = quad * 4 + i;
            #pragma unroll
            for (int nt = 0; nt < 4; ++nt) {
                unsigned short h, l;
                split_bf16(p[nt][i], h, l);
                unsigned hx = (unsigned)__shfl_xor((int)h, 1);
                unsigned lx = (unsigned)__shfl_xor((int)l, 1);
                int e = (row * 64 + nt * 16 + (ln & ~1)) ^ ((row & 7) << 3);
                if ((ln & 1) == 0) *(unsigned*)&php[e] = (unsigned)h | (hx << 16);
                else               *(unsigned*)&plp[e] = lx | ((unsigned)l << 16);
            }
        }

        // ---- O += P V  (A = P rows q=ln; B = V^T rows d=nt*16+ln) ----
        #pragma unroll
        for (int kk = 0; kk < 2; ++kk) {
            int ea = (ln * 64 + kk * 32 + quad * 8) ^ ((ln & 7) << 3);
            bf16x8 pah = *(const bf16x8*)&php[ea];
            bf16x8 pal = *(const bf16x8*)&plp[ea];
            #pragma unroll
            for (int nt = 0; nt < 4; ++nt) {
                int eb = ((nt * 16 + ln) * 64 + kk * 32 + quad * 8) ^ ((ln & 7) << 3);
                bf16x8 vbh = *(const bf16x8*)&Vth[eb];
                bf16x8 vbl = *(const bf16x8*)&Vtl[eb];
                acc_o[nt] = __builtin_amdgcn_mfma_f32_16x16x32_bf16(pah, vbh, acc_o[nt], 0, 0, 0);
                acc_o[nt] = __builtin_amdgcn_mfma_f32_16x16x32_bf16(pah, vbl, acc_o[nt], 0, 0, 0);
                acc_o[nt] = __builtin_amdgcn_mfma_f32_16x16x32_bf16(pal, vbh, acc_o[nt], 0, 0, 0);
            }
        }
        __syncthreads();
    }

    // ---- epilogue: O row = quad*4+i, col = nt*16+ln ----
    #pragma unroll
    for (int i = 0; i < 4; ++i) {
        int tok = q0 + wave * 16 + quad * 4 + i;
        if (tok >= T) continue;
        float inv = 1.f / lsum[i];
        size_t rowb = (size_t)(img * 577 + tok) * 768 + head * 64;
        #pragma unroll
        for (int nt = 0; nt < 4; ++nt) {
            unsigned short h, l;
            split_bf16(acc_o[nt][i] * inv, h, l);
            Oh[rowb + nt * 16 + ln] = h;
            Ol[rowb + nt * 16 + ln] = l;
        }
    }
}

// ---------------- final LN(cls) + cosine loss -------------------------------
__global__ __launch_bounds__(256)
void final_k(const float* __restrict__ X, const float* __restrict__ g,
             const float* __restrict__ b, float* __restrict__ out)
{
    __shared__ float F[4][768];
    __shared__ float rs[4], rss[4];
    __shared__ float rd[4], rna[4], rnb[4];
    __shared__ float cosv[2];
    int tid = threadIdx.x;
    for (int rr = 0; rr < 4; ++rr) {
        const float* x = X + (size_t)rr * 577 * 768;
        float v0 = x[tid], v1 = x[tid + 256], v2 = x[tid + 512];
        float s = v0 + v1 + v2;
        float ss = v0 * v0 + v1 * v1 + v2 * v2;
        for (int off = 32; off; off >>= 1) {
            s  += __shfl_xor(s, off, 64);
            ss += __shfl_xor(ss, off, 64);
        }
        if ((tid & 63) == 0) { rs[tid >> 6] = s; rss[tid >> 6] = ss; }
        __syncthreads();
        s  = rs[0] + rs[1] + rs[2] + rs[3];
        ss = rss[0] + rss[1] + rss[2] + rss[3];
        float mu  = s * (1.f / 768.f);
        float var = ss * (1.f / 768.f) - mu * mu;
        float inv = rsqrtf(var + 1e-6f);
        F[rr][tid]       = (v0 - mu) * inv * g[tid]       + b[tid];
        F[rr][tid + 256] = (v1 - mu) * inv * g[tid + 256] + b[tid + 256];
        F[rr][tid + 512] = (v2 - mu) * inv * g[tid + 512] + b[tid + 512];
        __syncthreads();
    }
    for (int bb = 0; bb < 2; ++bb) {
        float d = 0.f, na = 0.f, nb = 0.f;
        for (int u = tid; u < 768; u += 256) {
            float fa = F[bb][u], fb = F[bb + 2][u];
            d += fa * fb; na += fa * fa; nb += fb * fb;
        }
        for (int off = 32; off; off >>= 1) {
            d  += __shfl_xor(d, off, 64);
            na += __shfl_xor(na, off, 64);
            nb += __shfl_xor(nb, off, 64);
        }
        if ((tid & 63) == 0) { rd[tid >> 6] = d; rna[tid >> 6] = na; rnb[tid >> 6] = nb; }
        __syncthreads();
        if (tid == 0) {
            float D  = rd[0] + rd[1] + rd[2] + rd[3];
            float NA = sqrtf(rna[0] + rna[1] + rna[2] + rna[3]);
            float NB = sqrtf(rnb[0] + rnb[1] + rnb[2] + rnb[3]);
            cosv[bb] = D / (fmaxf(NA, 1e-8f) * fmaxf(NB, 1e-8f));
        }
        __syncthreads();
    }
    if (tid == 0) out[0] = 1.f - 0.5f * (cosv[0] + cosv[1]);
}

// ---------------- host orchestration ----------------------------------------
extern "C" void kernel_launch(void* const* d_in, const int* in_sizes, int n_in,
                              void* d_out, int out_size, void* d_ws, size_t ws_size,
                              hipStream_t stream)
{
    const float* logits  = (const float*)d_in[0];
    const int*   truem   = (const int*)d_in[1];
    const float* patch_w = (const float*)d_in[2];
    const float* patch_b = (const float*)d_in[3];
    const float* cls_tok = (const float*)d_in[4];
    const float* pos_emb = (const float*)d_in[5];
    const float* ln1_g   = (const float*)d_in[6];
    const float* ln1_b   = (const float*)d_in[7];
    const float* qkv_w   = (const float*)d_in[8];
    const float* qkv_b   = (const float*)d_in[9];
    const float* proj_w  = (const float*)d_in[10];
    const float* proj_b  = (const float*)d_in[11];
    const float* ln2_g   = (const float*)d_in[12];
    const float* ln2_b   = (const float*)d_in[13];
    const float* fc1_w   = (const float*)d_in[14];
    const float* fc1_b   = (const float*)d_in[15];
    const float* fc2_w   = (const float*)d_in[16];
    const float* fc2_b   = (const float*)d_in[17];
    const float* norm_g  = (const float*)d_in[18];
    const float* norm_b  = (const float*)d_in[19];

    char* p = (char*)d_ws;
    float* X             = (float*)(p + 0);              //  7,090,176 B (2308x768 f32)
    float* QKV           = (float*)(p + 7090176);        // 21,270,528 B (2308x2304 f32)
    unsigned short* qkvTh = (unsigned short*)(p + 28360704);  // 2304x768
    unsigned short* qkvTl = (unsigned short*)(p + 31899648);
    unsigned short* projTh= (unsigned short*)(p + 35438592);  // 768x768
    unsigned short* projTl= (unsigned short*)(p + 36618240);
    unsigned short* fc1Th = (unsigned short*)(p + 37797888);  // 3072x768
    unsigned short* fc1Tl = (unsigned short*)(p + 42516480);
    unsigned short* fc2Th = (unsigned short*)(p + 47235072);  // 768x3072
    unsigned short* fc2Tl = (unsigned short*)(p + 51953664);
    unsigned short* Hh    = (unsigned short*)(p + 56672256);  // 2432x768
    unsigned short* Hl    = (unsigned short*)(p + 60407808);
    unsigned short* Oh    = (unsigned short*)(p + 64143360);  // 2432x768
    unsigned short* Ol    = (unsigned short*)(p + 67878912);
    unsigned short* MIDh  = (unsigned short*)(p + 71614464);  // 2432x3072
    unsigned short* MIDl  = (unsigned short*)(p + 86556672);
    // EDT/patch phase overlays (dead before layer loop uses the regions):
    float* g2o   = (float*)MIDh;
    float* g2z   = g2o + 589824;
    float* sdm   = (float*)MIDl;
    unsigned short* pvh = Hh;
    unsigned short* pvl = Hl;
    float* Weff  = (float*)Oh;           // 256x768 f32
    unsigned short* WeffTh = qkvTh;      // 768x256
    unsigned short* WeffTl = qkvTl;
    float* tokb  = QKV;                  // 2304x768 f32

    edt_rows_k<<<1536, 64, 0, stream>>>(logits, truem, g2o, g2z);
    edt_cols_k<<<dim3(48, 4), 256, 0, stream>>>(g2o, g2z, sdm);
    weff_k<<<768, 256, 0, stream>>>(patch_w, Weff);
    tconv_k<<<192, 256, 0, stream>>>(Weff, WeffTh, WeffTl, 256, 768);
    pvec_split_k<<<2304, 256, 0, stream>>>(sdm, pvh, pvl);
    gemm_bt_k<0><<<dim3(6, 18), 256, 0, stream>>>(pvh, pvl, WeffTh, WeffTl, patch_b,
                                                  nullptr, tokb, nullptr, nullptr,
                                                  2304, 768, 256);
    addpos_k<<<6924, 256, 0, stream>>>(tokb, cls_tok, pos_emb, X);

    for (int l = 0; l < 12; ++l) {
        wconv_layer_k<<<6912, 256, 0, stream>>>(
            qkv_w + (size_t)l * 768 * 2304, proj_w + (size_t)l * 768 * 768,
            fc1_w + (size_t)l * 768 * 3072, fc2_w + (size_t)l * 3072 * 768,
            qkvTh, qkvTl, projTh, projTl, fc1Th, fc1Tl, fc2Th, fc2Tl);
        ln_split_k<<<2308, 256, 0, stream>>>(X, ln1_g + l * 768, ln1_b + l * 768, Hh, Hl);
        gemm_bt_k<0><<<dim3(18, 19), 256, 0, stream>>>(Hh, Hl, qkvTh, qkvTl,
                                                       qkv_b + l * 2304, nullptr, QKV,
                                                       nullptr, nullptr, 2308, 2304, 768);
        attn_k<<<dim3(10, 12, 4), 256, 0, stream>>>(QKV, Oh, Ol);
        gemm_bt_k<2><<<dim3(6, 19), 256, 0, stream>>>(Oh, Ol, projTh, projTl,
                                                      proj_b + l * 768, X, X,
                                                      nullptr, nullptr, 2308, 768, 768);
        ln_split_k<<<2308, 256, 0, stream>>>(X, ln2_g + l * 768, ln2_b + l * 768, Hh, Hl);
        gemm_bt_k<1><<<dim3(24, 19), 256, 0, stream>>>(Hh, Hl, fc1Th, fc1Tl,
                                                       fc1_b + l * 3072, nullptr, nullptr,
                                                       MIDh, MIDl, 2308, 3072, 768);
        gemm_bt_k<2><<<dim3(6, 19), 256, 0, stream>>>(MIDh, MIDl, fc2Th, fc2Tl,
                                                      fc2_b + l * 768, X, X,
                                                      nullptr, nullptr, 2308, 768, 3072);
    }
    final_k<<<1, 256, 0, stream>>>(X, norm_g, norm_b, (float*)d_out);
}

// Round 2
// 4105.562 us; speedup vs baseline: 1.2467x; 1.2199x over previous
//
#include <hip/hip_runtime.h>
#include <hip/hip_bf16.h>
#include <math.h>

#define BIGF 1e4f

typedef __attribute__((ext_vector_type(8))) short bf16x8;
typedef __attribute__((ext_vector_type(4))) float f32x4;

__device__ __forceinline__ unsigned short f2bf_rne(float v) {
    unsigned u = __float_as_uint(v);
    return (unsigned short)((u + 0x7FFFu + ((u >> 16) & 1u)) >> 16);
}
__device__ __forceinline__ void split_bf16(float v, unsigned short& h, unsigned short& l) {
    unsigned u = __float_as_uint(v);
    unsigned hr = (u + 0x7FFFu + ((u >> 16) & 1u)) >> 16;
    h = (unsigned short)hr;
    float hf = __uint_as_float(hr << 16);
    l = f2bf_rne(v - hf);
}

// async global->LDS, 16B per lane, wave-uniform LDS base + lane*16
__device__ __forceinline__ void gl16(const unsigned short* g, unsigned short* l) {
    __builtin_amdgcn_global_load_lds(
        (const __attribute__((address_space(1))) unsigned int*)g,
        (__attribute__((address_space(3))) unsigned int*)l, 16, 0, 0);
}

// ---------------- EDT row pass ----------------------------------------------
__global__ __launch_bounds__(64)
void edt_rows_k(const float* __restrict__ logits, const int* __restrict__ truem,
                float* __restrict__ g2o, float* __restrict__ g2z)
{
    int blk = blockIdx.x;
    int a = blk / 384, row = blk % 384;
    int lane = threadIdx.x;
    int j0 = lane * 6;
    float mk[6];
    if (a < 2) {
        const float* l0 = logits + (size_t)a * 2 * 147456 + (size_t)row * 384;
        const float* l1 = l0 + 147456;
        #pragma unroll
        for (int u = 0; u < 6; ++u) mk[u] = (l1[j0+u] > l0[j0+u]) ? 1.f : 0.f;
    } else {
        const int* t = truem + (size_t)(a - 2) * 147456 + (size_t)row * 384;
        #pragma unroll
        for (int u = 0; u < 6; ++u) mk[u] = (t[j0+u] != 0) ? 1.f : 0.f;
    }
    float lo[6], lz[6], ro[6], rz[6];
    float run_lo = -BIGF, run_lz = -BIGF;
    #pragma unroll
    for (int u = 0; u < 6; ++u) {
        float jf = (float)(j0 + u);
        if (mk[u] > 0.5f) run_lo = jf; else run_lz = jf;
        lo[u] = run_lo; lz[u] = run_lz;
    }
    float inc_o = run_lo, inc_z = run_lz;
    for (int off = 1; off < 64; off <<= 1) {
        float to = __shfl_up(inc_o, off), tz = __shfl_up(inc_z, off);
        if (lane >= off) { inc_o = fmaxf(inc_o, to); inc_z = fmaxf(inc_z, tz); }
    }
    float ex_o = __shfl_up(inc_o, 1); if (lane == 0) ex_o = -BIGF;
    float ex_z = __shfl_up(inc_z, 1); if (lane == 0) ex_z = -BIGF;

    float run_ro = BIGF, run_rz = BIGF;
    #pragma unroll
    for (int u = 5; u >= 0; --u) {
        float jf = (float)(j0 + u);
        if (mk[u] > 0.5f) run_ro = jf; else run_rz = jf;
        ro[u] = run_ro; rz[u] = run_rz;
    }
    float in2_o = run_ro, in2_z = run_rz;
    for (int off = 1; off < 64; off <<= 1) {
        float to = __shfl_down(in2_o, off), tz = __shfl_down(in2_z, off);
        if (lane + off < 64) { in2_o = fminf(in2_o, to); in2_z = fminf(in2_z, tz); }
    }
    float sx_o = __shfl_down(in2_o, 1); if (lane == 63) sx_o = BIGF;
    float sx_z = __shfl_down(in2_z, 1); if (lane == 63) sx_z = BIGF;

    size_t ob = (size_t)a * 147456 + (size_t)row * 384;
    #pragma unroll
    for (int u = 0; u < 6; ++u) {
        float jf = (float)(j0 + u);
        float dlo = jf - fmaxf(lo[u], ex_o);
        float dro = fminf(ro[u], sx_o) - jf;
        float go = fminf(fminf(dlo, dro), BIGF);
        float dlz = jf - fmaxf(lz[u], ex_z);
        float drz = fminf(rz[u], sx_z) - jf;
        float gz = fminf(fminf(dlz, drz), BIGF);
        g2o[ob + j0 + u] = go * go;
        g2z[ob + j0 + u] = gz * gz;
    }
}

// ---------------- EDT column pass -------------------------------------------
__global__ __launch_bounds__(256)
void edt_cols_k(const float* __restrict__ g2o, const float* __restrict__ g2z,
                float* __restrict__ sdm)
{
    int a = blockIdx.y;
    int w0 = blockIdx.x * 8;
    __shared__ float so[384][8];
    __shared__ float sz[384][8];
    int tid = threadIdx.x;
    for (int h = 0; h < 12; ++h) {
        int lin = tid + 256 * h;
        int ip = lin >> 3, ww = lin & 7;
        so[ip][ww] = g2o[(size_t)a * 147456 + (size_t)ip * 384 + w0 + ww];
        sz[ip][ww] = g2z[(size_t)a * 147456 + (size_t)ip * 384 + w0 + ww];
    }
    __syncthreads();
    int w = tid & 7, ib = tid >> 3;
    float vo[12], vz[12];
    #pragma unroll
    for (int r = 0; r < 12; ++r) { vo[r] = 3.4e38f; vz[r] = 3.4e38f; }
    for (int ip = 0; ip < 384; ++ip) {
        float go = so[ip][w], gz = sz[ip][w];
        #pragma unroll
        for (int r = 0; r < 12; ++r) {
            float d = (float)(ib + 32 * r - ip);
            float dd = d * d;
            vo[r] = fminf(vo[r], dd + go);
            vz[r] = fminf(vz[r], dd + gz);
        }
    }
    #pragma unroll
    for (int r = 0; r < 12; ++r) {
        sdm[(size_t)a * 147456 + (size_t)(ib + 32 * r) * 384 + w0 + w] =
            sqrtf(vo[r]) - sqrtf(vz[r]);
    }
}

// ---------------- channel-reduced patch weight ------------------------------
__global__ void weff_k(const float* __restrict__ pw, float* __restrict__ W)
{
    int i = blockIdx.x * 256 + threadIdx.x;
    if (i < 196608) W[i] = pw[i] + pw[i + 196608] + pw[i + 393216];
}

// ---------------- generic transpose + split: [K,N] f32 -> [N,K] bf16 h/l ----
__global__ __launch_bounds__(256)
void tconv_k(const float* __restrict__ src, unsigned short* __restrict__ dh,
             unsigned short* __restrict__ dl, int K, int N)
{
    __shared__ float tile[32][33];
    int t = blockIdx.x;
    int ntk = K >> 5;
    int tn = t / ntk, tk = t % ntk;
    int tid = threadIdx.x;
    int tx = tid & 31, ty = tid >> 5;
    #pragma unroll
    for (int i = 0; i < 4; ++i) {
        int k = tk * 32 + ty + i * 8;
        tile[ty + i * 8][tx] = src[(size_t)k * N + tn * 32 + tx];
    }
    __syncthreads();
    #pragma unroll
    for (int i = 0; i < 4; ++i) {
        int n = tn * 32 + ty + i * 8;
        float v = tile[tx][ty + i * 8];
        unsigned short h, l;
        split_bf16(v, h, l);
        dh[(size_t)n * K + tk * 32 + tx] = h;
        dl[(size_t)n * K + tk * 32 + tx] = l;
    }
}

// ---------------- fused per-layer weight transpose+split --------------------
__global__ __launch_bounds__(256)
void wconv_layer_k(const float* __restrict__ qkv, const float* __restrict__ proj,
                   const float* __restrict__ fc1, const float* __restrict__ fc2,
                   unsigned short* qkvTh, unsigned short* qkvTl,
                   unsigned short* projTh, unsigned short* projTl,
                   unsigned short* fc1Th, unsigned short* fc1Tl,
                   unsigned short* fc2Th, unsigned short* fc2Tl)
{
    __shared__ float tile[32][33];
    int t = blockIdx.x;
    const float* src; unsigned short *dh, *dl; int K, N, tt;
    if (t < 1728)      { src = qkv;  dh = qkvTh;  dl = qkvTl;  K = 768;  N = 2304; tt = t; }
    else if (t < 2304) { src = proj; dh = projTh; dl = projTl; K = 768;  N = 768;  tt = t - 1728; }
    else if (t < 4608) { src = fc1;  dh = fc1Th;  dl = fc1Tl;  K = 768;  N = 3072; tt = t - 2304; }
    else               { src = fc2;  dh = fc2Th;  dl = fc2Tl;  K = 3072; N = 768;  tt = t - 4608; }
    int ntk = K >> 5;
    int tn = tt / ntk, tk = tt % ntk;
    int tid = threadIdx.x;
    int tx = tid & 31, ty = tid >> 5;
    #pragma unroll
    for (int i = 0; i < 4; ++i) {
        int k = tk * 32 + ty + i * 8;
        tile[ty + i * 8][tx] = src[(size_t)k * N + tn * 32 + tx];
    }
    __syncthreads();
    #pragma unroll
    for (int i = 0; i < 4; ++i) {
        int n = tn * 32 + ty + i * 8;
        float v = tile[tx][ty + i * 8];
        unsigned short h, l;
        split_bf16(v, h, l);
        dh[(size_t)n * K + tk * 32 + tx] = h;
        dl[(size_t)n * K + tk * 32 + tx] = l;
    }
}

// ---------------- gather patch vectors, split -------------------------------
__global__ void pvec_split_k(const float* __restrict__ sdm,
                             unsigned short* __restrict__ ph,
                             unsigned short* __restrict__ pl)
{
    int idx = blockIdx.x * 256 + threadIdx.x;   // 589824 total
    int cc = idx & 15, r = (idx >> 4) & 15, p = idx >> 8;
    int px = p % 24, py = (p / 24) % 24, aa = p / 576;
    float v = sdm[(size_t)aa * 147456 + (size_t)(py * 16 + r) * 384 + px * 16 + cc];
    unsigned short h, l;
    split_bf16(v, h, l);
    ph[idx] = h; pl[idx] = l;
}

// ---------------- cls + pos assembly ---------------------------------------
__global__ void addpos_k(const float* __restrict__ tok, const float* __restrict__ cls,
                         const float* __restrict__ pos, float* __restrict__ X)
{
    int idx = blockIdx.x * 256 + threadIdx.x;
    if (idx >= 1772544) return;
    int d = idx % 768;
    int t = (idx / 768) % 577;
    int img = idx / (768 * 577);
    float v;
    if (t == 0) v = cls[d] + pos[d];
    else v = tok[((size_t)img * 576 + (t - 1)) * 768 + d] + pos[(size_t)t * 768 + d];
    X[idx] = v;
}

// ---------------- LayerNorm -> split bf16 -----------------------------------
__global__ __launch_bounds__(256)
void ln_split_k(const float* __restrict__ X, const float* __restrict__ g,
                const float* __restrict__ b, unsigned short* __restrict__ Yh,
                unsigned short* __restrict__ Yl)
{
    int row = blockIdx.x;
    const float* x = X + (size_t)row * 768;
    int tid = threadIdx.x;
    __shared__ float rs[4], rss[4];
    float v0 = x[tid], v1 = x[tid + 256], v2 = x[tid + 512];
    float s = v0 + v1 + v2;
    float ss = v0 * v0 + v1 * v1 + v2 * v2;
    for (int off = 32; off; off >>= 1) {
        s  += __shfl_xor(s, off, 64);
        ss += __shfl_xor(ss, off, 64);
    }
    if ((tid & 63) == 0) { rs[tid >> 6] = s; rss[tid >> 6] = ss; }
    __syncthreads();
    s  = rs[0] + rs[1] + rs[2] + rs[3];
    ss = rss[0] + rss[1] + rss[2] + rss[3];
    float mu  = s * (1.f / 768.f);
    float var = ss * (1.f / 768.f) - mu * mu;
    float inv = rsqrtf(var + 1e-6f);
    unsigned short h, l;
    float y0 = (v0 - mu) * inv * g[tid]       + b[tid];
    float y1 = (v1 - mu) * inv * g[tid + 256] + b[tid + 256];
    float y2 = (v2 - mu) * inv * g[tid + 512] + b[tid + 512];
    size_t base = (size_t)row * 768;
    split_bf16(y0, h, l); Yh[base + tid]       = h; Yl[base + tid]       = l;
    split_bf16(y1, h, l); Yh[base + tid + 256] = h; Yl[base + tid + 256] = l;
    split_bf16(y2, h, l); Yh[base + tid + 512] = h; Yl[base + tid + 512] = l;
}

// ---------------- split-bf16 MFMA GEMM (dbuf + optional split-K) -----------
// A: Ah/Al [M,K] bf16 row-major (M padded to 128-mult in memory)
// B: Bh/Bl [N,K] bf16 row-major (pre-transposed weights)
// OP: 0 = store fp32 Cf, 1 = gelu -> split bf16 Ch/Cl, 2 = fp32 residual Cf=acc+bias+R
// KSPLIT>1: blockIdx.z = K-chunk; kc==0 does the OP epilogue, kc>0 writes raw
// f32 partials to Part[(kc-1)*M*N + r*N + c] (combine3_k folds them in).
// Double-buffered LDS (2x32KB), one __syncthreads per K-step: next tile's
// global_load_lds fly during current tile's MFMA, drained by the barrier.
template<int OP, int KSPLIT>
__global__ __launch_bounds__(256, 2)
void gemm_bt_k(const unsigned short* __restrict__ Ah_g, const unsigned short* __restrict__ Al_g,
               const unsigned short* __restrict__ Bh_g, const unsigned short* __restrict__ Bl_g,
               const float* __restrict__ bias, const float* __restrict__ R,
               float* __restrict__ Cf, unsigned short* __restrict__ Ch,
               unsigned short* __restrict__ Cl, float* __restrict__ Part,
               int M, int N, int K)
{
    __shared__ unsigned short LDS[2][16384];   // per buf: Ah|Al|Bh|Bl, 4096 each

    int tid = threadIdx.x;
    int lane = tid & 63, wave = tid >> 6;
    int bn = blockIdx.x * 128, bm = blockIdx.y * 128;
    int ln = lane & 15, quad = lane >> 4;
    int wm = (wave >> 1) * 64, wn = (wave & 1) * 64;

    int klen = K / KSPLIT;
    int kbeg = (KSPLIT > 1) ? blockIdx.z * klen : 0;

    // staging: each wave stages rows [wave*32, wave*32+32) of each tile,
    // 16 rows per global_load_lds (64 lanes x 16B = 1KB = 16 rows x 64B)
    int srow = wave * 32 + (lane >> 2);
    int scol = (lane & 3) * 8;
    const unsigned short* pAh = Ah_g + (size_t)(bm + srow) * K + kbeg + scol;
    const unsigned short* pAl = Al_g + (size_t)(bm + srow) * K + kbeg + scol;
    const unsigned short* pBh = Bh_g + (size_t)(bn + srow) * K + kbeg + scol;
    const unsigned short* pBl = Bl_g + (size_t)(bn + srow) * K + kbeg + scol;
    size_t rstep = (size_t)16 * K;

    f32x4 acc[4][4] = {};
    int ntiles = klen >> 5;

    // prologue: stage tile 0 into buf 0
    {
        unsigned short* d = &LDS[0][wave * 1024];
        gl16(pAh, d);          gl16(pAh + rstep, d + 512);
        gl16(pAl, d + 4096);   gl16(pAl + rstep, d + 4608);
        gl16(pBh, d + 8192);   gl16(pBh + rstep, d + 8704);
        gl16(pBl, d + 12288);  gl16(pBl + rstep, d + 12800);
    }
    __syncthreads();

    for (int t = 0; t < ntiles; ++t) {
        if (t + 1 < ntiles) {
            int k0 = (t + 1) << 5;
            unsigned short* d = &LDS[(t + 1) & 1][wave * 1024];
            gl16(pAh + k0, d);          gl16(pAh + k0 + rstep, d + 512);
            gl16(pAl + k0, d + 4096);   gl16(pAl + k0 + rstep, d + 4608);
            gl16(pBh + k0, d + 8192);   gl16(pBh + k0 + rstep, d + 8704);
            gl16(pBl + k0, d + 12288);  gl16(pBl + k0 + rstep, d + 12800);
        }
        const unsigned short* Ah = &LDS[t & 1][0];
        const unsigned short* Al = Ah + 4096;
        const unsigned short* Bh = Ah + 8192;
        const unsigned short* Bl = Ah + 12288;

        bf16x8 fbh[4], fbl[4];
        #pragma unroll
        for (int nt = 0; nt < 4; ++nt) {
            fbh[nt] = *(const bf16x8*)&Bh[(wn + nt * 16 + ln) * 32 + quad * 8];
            fbl[nt] = *(const bf16x8*)&Bl[(wn + nt * 16 + ln) * 32 + quad * 8];
        }
        #pragma unroll
        for (int mt = 0; mt < 4; ++mt) {
            bf16x8 fah = *(const bf16x8*)&Ah[(wm + mt * 16 + ln) * 32 + quad * 8];
            bf16x8 fal = *(const bf16x8*)&Al[(wm + mt * 16 + ln) * 32 + quad * 8];
            #pragma unroll
            for (int nt = 0; nt < 4; ++nt) {
                acc[mt][nt] = __builtin_amdgcn_mfma_f32_16x16x32_bf16(fah, fbh[nt], acc[mt][nt], 0, 0, 0);
                acc[mt][nt] = __builtin_amdgcn_mfma_f32_16x16x32_bf16(fah, fbl[nt], acc[mt][nt], 0, 0, 0);
                acc[mt][nt] = __builtin_amdgcn_mfma_f32_16x16x32_bf16(fal, fbh[nt], acc[mt][nt], 0, 0, 0);
            }
        }
        __syncthreads();   // drains next-tile loads (vmcnt 0) + readers done
    }

    // epilogue: D row = quad*4 + i, col = ln
    if (KSPLIT > 1 && blockIdx.z > 0) {
        float* P = Part + (size_t)(blockIdx.z - 1) * ((size_t)M * N);
        #pragma unroll
        for (int mt = 0; mt < 4; ++mt) {
            #pragma unroll
            for (int i = 0; i < 4; ++i) {
                int r = bm + wm + mt * 16 + quad * 4 + i;
                if (r >= M) continue;
                #pragma unroll
                for (int nt = 0; nt < 4; ++nt) {
                    int c = bn + wn + nt * 16 + ln;
                    P[(size_t)r * N + c] = acc[mt][nt][i];
                }
            }
        }
        return;
    }
    #pragma unroll
    for (int mt = 0; mt < 4; ++mt) {
        #pragma unroll
        for (int i = 0; i < 4; ++i) {
            int r = bm + wm + mt * 16 + quad * 4 + i;
            if (r >= M) continue;
            #pragma unroll
            for (int nt = 0; nt < 4; ++nt) {
                int c = bn + wn + nt * 16 + ln;
                float v = acc[mt][nt][i] + bias[c];
                if (OP == 0) {
                    Cf[(size_t)r * N + c] = v;
                } else if (OP == 1) {
                    v = 0.5f * v * (1.f + erff(v * 0.70710678118654752f));
                    unsigned short h, l;
                    split_bf16(v, h, l);
                    Ch[(size_t)r * N + c] = h;
                    Cl[(size_t)r * N + c] = l;
                } else {
                    Cf[(size_t)r * N + c] = v + R[(size_t)r * N + c];
                }
            }
        }
    }
}

// ---------------- split-K combine: X += P0 + P1 + P2 ------------------------
__global__ __launch_bounds__(256)
void combine3_k(float* __restrict__ X, const float* __restrict__ P)
{
    int i = blockIdx.x * 256 + threadIdx.x;          // 443136 float4s total
    float4 x = ((float4*)X)[i];
    float4 a = ((const float4*)P)[i];
    float4 b = ((const float4*)P)[i + 443136];
    float4 c = ((const float4*)P)[i + 886272];
    x.x += a.x + b.x + c.x;
    x.y += a.y + b.y + c.y;
    x.z += a.z + b.z + c.z;
    x.w += a.w + b.w + c.w;
    ((float4*)X)[i] = x;
}

// ---------------- MFMA flash attention (split-bf16) -------------------------
__global__ __launch_bounds__(256)
void attn_k(const float* __restrict__ QKV, unsigned short* __restrict__ Oh,
            unsigned short* __restrict__ Ol)
{
    const int T = 577;
    int img = blockIdx.z, head = blockIdx.y;
    int q0 = blockIdx.x * 64;
    const float* base = QKV + (size_t)img * T * 2304;

    __shared__ unsigned short Ksh[64 * 64], Ksl[64 * 64];   // K  [tok][d]
    __shared__ unsigned short Vth[64 * 64], Vtl[64 * 64];   // V^T [d][tok]
    __shared__ unsigned short Psh[4][16 * 64], Psl[4][16 * 64]; // per-wave P [q][tok]

    int tid = threadIdx.x;
    int wave = tid >> 6, lane = tid & 63;
    int ln = lane & 15, quad = lane >> 4;

    // ---- Q fragments: A-frag row q = ln, d = kk*32 + quad*8 (x0.125) ----
    bf16x8 qh[2], qlo[2];
    {
        int qtok = q0 + wave * 16 + ln;
        const float* qp = base + (size_t)qtok * 2304 + head * 64 + quad * 8;
        #pragma unroll
        for (int kk = 0; kk < 2; ++kk) {
            #pragma unroll
            for (int u = 0; u < 8; ++u) {
                float v = 0.f;
                if (qtok < T) v = qp[kk * 32 + u] * 0.125f;
                unsigned short h, l;
                split_bf16(v, h, l);
                qh[kk][u] = (short)h; qlo[kk][u] = (short)l;
            }
        }
    }

    float m[4], lsum[4];
    f32x4 acc_o[4] = {};          // O: row q = quad*4+i, col d = nt*16+ln
    #pragma unroll
    for (int i = 0; i < 4; ++i) { m[i] = -1e30f; lsum[i] = 0.f; }

    int kd  = lane;               // K staging: lane = d
    int vr0 = (tid >> 3) * 2;     // V staging: token pair
    int vdc = tid & 7;            // V staging: d column base

    for (int c0 = 0; c0 < T; c0 += 64) {
        // ---- stage K [tok][d] ----
        #pragma unroll
        for (int it = 0; it < 16; ++it) {
            int r = wave * 16 + it;
            float v = 0.f;
            if (c0 + r < T) v = base[(size_t)(c0 + r) * 2304 + 768 + head * 64 + kd];
            unsigned short h, l;
            split_bf16(v, h, l);
            unsigned hx = (unsigned)__shfl_xor((int)h, 1);
            unsigned lx = (unsigned)__shfl_xor((int)l, 1);
            int e = (r * 64 + (kd & ~1)) ^ ((r & 7) << 3);
            if ((kd & 1) == 0) *(unsigned*)&Ksh[e] = (unsigned)h | (hx << 16);
            else               *(unsigned*)&Ksl[e] = lx | ((unsigned)l << 16);
        }
        // ---- stage V^T [d][tok] ----
        {
            const float* vp0 = base + (size_t)(c0 + vr0) * 2304 + 1536 + head * 64 + vdc;
            bool ok0 = (c0 + vr0) < T, ok1 = (c0 + vr0 + 1) < T;
            #pragma unroll
            for (int u = 0; u < 8; ++u) {
                float a = 0.f, b = 0.f;
                if (ok0) a = vp0[8 * u];
                if (ok1) b = vp0[2304 + 8 * u];
                unsigned short ha, la, hb, lb;
                split_bf16(a, ha, la);
                split_bf16(b, hb, lb);
                int d = vdc + 8 * u;
                int e = (d * 64 + vr0) ^ ((d & 7) << 3);
                *(unsigned*)&Vth[e] = (unsigned)ha | ((unsigned)hb << 16);
                *(unsigned*)&Vtl[e] = (unsigned)la | ((unsigned)lb << 16);
            }
        }
        __syncthreads();

        // ---- S = Q K^T (split 3-term) ----
        f32x4 s4[4] = {};
        #pragma unroll
        for (int nt = 0; nt < 4; ++nt) {
            int row = nt * 16 + ln;
            #pragma unroll
            for (int kk = 0; kk < 2; ++kk) {
                int e = (row * 64 + kk * 32 + quad * 8) ^ ((ln & 7) << 3);
                bf16x8 kbh = *(const bf16x8*)&Ksh[e];
                bf16x8 kbl = *(const bf16x8*)&Ksl[e];
                s4[nt] = __builtin_amdgcn_mfma_f32_16x16x32_bf16(qh[kk],  kbh, s4[nt], 0, 0, 0);
                s4[nt] = __builtin_amdgcn_mfma_f32_16x16x32_bf16(qh[kk],  kbl, s4[nt], 0, 0, 0);
                s4[nt] = __builtin_amdgcn_mfma_f32_16x16x32_bf16(qlo[kk], kbh, s4[nt], 0, 0, 0);
            }
        }

        // ---- online softmax ----
        bool full = (c0 + 64 <= T);
        float p[4][4];
        #pragma unroll
        for (int i = 0; i < 4; ++i) {
            float mx = -1e30f;
            #pragma unroll
            for (int nt = 0; nt < 4; ++nt) {
                float sv = s4[nt][i];
                if (!full && (c0 + nt * 16 + ln >= T)) sv = -1e30f;
                p[nt][i] = sv;
                mx = fmaxf(mx, sv);
            }
            mx = fmaxf(mx, __shfl_xor(mx, 1));
            mx = fmaxf(mx, __shfl_xor(mx, 2));
            mx = fmaxf(mx, __shfl_xor(mx, 4));
            mx = fmaxf(mx, __shfl_xor(mx, 8));
            float mnew = fmaxf(m[i], mx);
            float alpha = __expf(m[i] - mnew);
            m[i] = mnew;
            float rsum = 0.f;
            #pragma unroll
            for (int nt = 0; nt < 4; ++nt) {
                float pv = __expf(p[nt][i] - mnew);
                p[nt][i] = pv;
                rsum += pv;
            }
            rsum += __shfl_xor(rsum, 1); rsum += __shfl_xor(rsum, 2);
            rsum += __shfl_xor(rsum, 4); rsum += __shfl_xor(rsum, 8);
            lsum[i] = lsum[i] * alpha + rsum;
            acc_o[0][i] *= alpha; acc_o[1][i] *= alpha;
            acc_o[2][i] *= alpha; acc_o[3][i] *= alpha;
        }

        // ---- P -> split bf16 into per-wave LDS tile (C-layout write) ----
        unsigned short* php = Psh[wave];
        unsigned short* plp = Psl[wave];
        #pragma unroll
        for (int i = 0; i < 4; ++i) {
            int row = quad * 4 + i;
            #pragma unroll
            for (int nt = 0; nt < 4; ++nt) {
                unsigned short h, l;
                split_bf16(p[nt][i], h, l);
                unsigned hx = (unsigned)__shfl_xor((int)h, 1);
                unsigned lx = (unsigned)__shfl_xor((int)l, 1);
                int e = (row * 64 + nt * 16 + (ln & ~1)) ^ ((row & 7) << 3);
                if ((ln & 1) == 0) *(unsigned*)&php[e] = (unsigned)h | (hx << 16);
                else               *(unsigned*)&plp[e] = lx | ((unsigned)l << 16);
            }
        }

        // ---- O += P V ----
        #pragma unroll
        for (int kk = 0; kk < 2; ++kk) {
            int ea = (ln * 64 + kk * 32 + quad * 8) ^ ((ln & 7) << 3);
            bf16x8 pah = *(const bf16x8*)&php[ea];
            bf16x8 pal = *(const bf16x8*)&plp[ea];
            #pragma unroll
            for (int nt = 0; nt < 4; ++nt) {
                int eb = ((nt * 16 + ln) * 64 + kk * 32 + quad * 8) ^ ((ln & 7) << 3);
                bf16x8 vbh = *(const bf16x8*)&Vth[eb];
                bf16x8 vbl = *(const bf16x8*)&Vtl[eb];
                acc_o[nt] = __builtin_amdgcn_mfma_f32_16x16x32_bf16(pah, vbh, acc_o[nt], 0, 0, 0);
                acc_o[nt] = __builtin_amdgcn_mfma_f32_16x16x32_bf16(pah, vbl, acc_o[nt], 0, 0, 0);
                acc_o[nt] = __builtin_amdgcn_mfma_f32_16x16x32_bf16(pal, vbh, acc_o[nt], 0, 0, 0);
            }
        }
        __syncthreads();
    }

    // ---- epilogue: O row = quad*4+i, col = nt*16+ln ----
    #pragma unroll
    for (int i = 0; i < 4; ++i) {
        int tok = q0 + wave * 16 + quad * 4 + i;
        if (tok >= T) continue;
        float inv = 1.f / lsum[i];
        size_t rowb = (size_t)(img * 577 + tok) * 768 + head * 64;
        #pragma unroll
        for (int nt = 0; nt < 4; ++nt) {
            unsigned short h, l;
            split_bf16(acc_o[nt][i] * inv, h, l);
            Oh[rowb + nt * 16 + ln] = h;
            Ol[rowb + nt * 16 + ln] = l;
        }
    }
}

// ---------------- final LN(cls) + cosine loss -------------------------------
__global__ __launch_bounds__(256)
void final_k(const float* __restrict__ X, const float* __restrict__ g,
             const float* __restrict__ b, float* __restrict__ out)
{
    __shared__ float F[4][768];
    __shared__ float rs[4], rss[4];
    __shared__ float rd[4], rna[4], rnb[4];
    __shared__ float cosv[2];
    int tid = threadIdx.x;
    for (int rr = 0; rr < 4; ++rr) {
        const float* x = X + (size_t)rr * 577 * 768;
        float v0 = x[tid], v1 = x[tid + 256], v2 = x[tid + 512];
        float s = v0 + v1 + v2;
        float ss = v0 * v0 + v1 * v1 + v2 * v2;
        for (int off = 32; off; off >>= 1) {
            s  += __shfl_xor(s, off, 64);
            ss += __shfl_xor(ss, off, 64);
        }
        if ((tid & 63) == 0) { rs[tid >> 6] = s; rss[tid >> 6] = ss; }
        __syncthreads();
        s  = rs[0] + rs[1] + rs[2] + rs[3];
        ss = rss[0] + rss[1] + rss[2] + rss[3];
        float mu  = s * (1.f / 768.f);
        float var = ss * (1.f / 768.f) - mu * mu;
        float inv = rsqrtf(var + 1e-6f);
        F[rr][tid]       = (v0 - mu) * inv * g[tid]       + b[tid];
        F[rr][tid + 256] = (v1 - mu) * inv * g[tid + 256] + b[tid + 256];
        F[rr][tid + 512] = (v2 - mu) * inv * g[tid + 512] + b[tid + 512];
        __syncthreads();
    }
    for (int bb = 0; bb < 2; ++bb) {
        float d = 0.f, na = 0.f, nb = 0.f;
        for (int u = tid; u < 768; u += 256) {
            float fa = F[bb][u], fb = F[bb + 2][u];
            d += fa * fb; na += fa * fa; nb += fb * fb;
        }
        for (int off = 32; off; off >>= 1) {
            d  += __shfl_xor(d, off, 64);
            na += __shfl_xor(na, off, 64);
            nb += __shfl_xor(nb, off, 64);
        }
        if ((tid & 63) == 0) { rd[tid >> 6] = d; rna[tid >> 6] = na; rnb[tid >> 6] = nb; }
        __syncthreads();
        if (tid == 0) {
            float D  = rd[0] + rd[1] + rd[2] + rd[3];
            float NA = sqrtf(rna[0] + rna[1] + rna[2] + rna[3]);
            float NB = sqrtf(rnb[0] + rnb[1] + rnb[2] + rnb[3]);
            cosv[bb] = D / (fmaxf(NA, 1e-8f) * fmaxf(NB, 1e-8f));
        }
        __syncthreads();
    }
    if (tid == 0) out[0] = 1.f - 0.5f * (cosv[0] + cosv[1]);
}

// ---------------- host orchestration ----------------------------------------
extern "C" void kernel_launch(void* const* d_in, const int* in_sizes, int n_in,
                              void* d_out, int out_size, void* d_ws, size_t ws_size,
                              hipStream_t stream)
{
    const float* logits  = (const float*)d_in[0];
    const int*   truem   = (const int*)d_in[1];
    const float* patch_w = (const float*)d_in[2];
    const float* patch_b = (const float*)d_in[3];
    const float* cls_tok = (const float*)d_in[4];
    const float* pos_emb = (const float*)d_in[5];
    const float* ln1_g   = (const float*)d_in[6];
    const float* ln1_b   = (const float*)d_in[7];
    const float* qkv_w   = (const float*)d_in[8];
    const float* qkv_b   = (const float*)d_in[9];
    const float* proj_w  = (const float*)d_in[10];
    const float* proj_b  = (const float*)d_in[11];
    const float* ln2_g   = (const float*)d_in[12];
    const float* ln2_b   = (const float*)d_in[13];
    const float* fc1_w   = (const float*)d_in[14];
    const float* fc1_b   = (const float*)d_in[15];
    const float* fc2_w   = (const float*)d_in[16];
    const float* fc2_b   = (const float*)d_in[17];
    const float* norm_g  = (const float*)d_in[18];
    const float* norm_b  = (const float*)d_in[19];

    char* p = (char*)d_ws;
    float* X             = (float*)(p + 0);              //  7,090,176 B (2308x768 f32)
    float* QKV           = (float*)(p + 7090176);        // 21,270,528 B (2308x2304 f32)
    unsigned short* qkvTh = (unsigned short*)(p + 28360704);  // 2304x768
    unsigned short* qkvTl = (unsigned short*)(p + 31899648);
    unsigned short* projTh= (unsigned short*)(p + 35438592);  // 768x768
    unsigned short* projTl= (unsigned short*)(p + 36618240);
    unsigned short* fc1Th = (unsigned short*)(p + 37797888);  // 3072x768
    unsigned short* fc1Tl = (unsigned short*)(p + 42516480);
    unsigned short* fc2Th = (unsigned short*)(p + 47235072);  // 768x3072
    unsigned short* fc2Tl = (unsigned short*)(p + 51953664);
    unsigned short* Hh    = (unsigned short*)(p + 56672256);  // 2432x768
    unsigned short* Hl    = (unsigned short*)(p + 60407808);
    unsigned short* Oh    = (unsigned short*)(p + 64143360);  // 2432x768
    unsigned short* Ol    = (unsigned short*)(p + 67878912);
    unsigned short* MIDh  = (unsigned short*)(p + 71614464);  // 2432x3072
    unsigned short* MIDl  = (unsigned short*)(p + 86556672);
    // EDT/patch phase overlays (dead before layer loop uses the regions):
    float* g2o   = (float*)MIDh;
    float* g2z   = g2o + 589824;
    float* sdm   = (float*)MIDl;
    unsigned short* pvh = Hh;
    unsigned short* pvl = Hl;
    float* Weff  = (float*)Oh;           // 256x768 f32
    unsigned short* WeffTh = qkvTh;      // 768x256
    unsigned short* WeffTl = qkvTl;
    float* tokb  = QKV;                  // 2304x768 f32
    float* Kpart = QKV;                  // split-K partials (3x 2308x768 f32 = QKV region)

    edt_rows_k<<<1536, 64, 0, stream>>>(logits, truem, g2o, g2z);
    edt_cols_k<<<dim3(48, 4), 256, 0, stream>>>(g2o, g2z, sdm);
    weff_k<<<768, 256, 0, stream>>>(patch_w, Weff);
    tconv_k<<<192, 256, 0, stream>>>(Weff, WeffTh, WeffTl, 256, 768);
    pvec_split_k<<<2304, 256, 0, stream>>>(sdm, pvh, pvl);
    gemm_bt_k<0, 1><<<dim3(6, 18), 256, 0, stream>>>(pvh, pvl, WeffTh, WeffTl, patch_b,
                                                     nullptr, tokb, nullptr, nullptr,
                                                     nullptr, 2304, 768, 256);
    addpos_k<<<6924, 256, 0, stream>>>(tokb, cls_tok, pos_emb, X);

    for (int l = 0; l < 12; ++l) {
        wconv_layer_k<<<6912, 256, 0, stream>>>(
            qkv_w + (size_t)l * 768 * 2304, proj_w + (size_t)l * 768 * 768,
            fc1_w + (size_t)l * 768 * 3072, fc2_w + (size_t)l * 3072 * 768,
            qkvTh, qkvTl, projTh, projTl, fc1Th, fc1Tl, fc2Th, fc2Tl);
        ln_split_k<<<2308, 256, 0, stream>>>(X, ln1_g + l * 768, ln1_b + l * 768, Hh, Hl);
        gemm_bt_k<0, 1><<<dim3(18, 19), 256, 0, stream>>>(Hh, Hl, qkvTh, qkvTl,
                                                          qkv_b + l * 2304, nullptr, QKV,
                                                          nullptr, nullptr, nullptr,
                                                          2308, 2304, 768);
        attn_k<<<dim3(10, 12, 4), 256, 0, stream>>>(QKV, Oh, Ol);
        gemm_bt_k<2, 4><<<dim3(6, 19, 4), 256, 0, stream>>>(Oh, Ol, projTh, projTl,
                                                            proj_b + l * 768, X, X,
                                                            nullptr, nullptr, Kpart,
                                                            2308, 768, 768);
        combine3_k<<<1731, 256, 0, stream>>>(X, Kpart);
        ln_split_k<<<2308, 256, 0, stream>>>(X, ln2_g + l * 768, ln2_b + l * 768, Hh, Hl);
        gemm_bt_k<1, 1><<<dim3(24, 19), 256, 0, stream>>>(Hh, Hl, fc1Th, fc1Tl,
                                                          fc1_b + l * 3072, nullptr, nullptr,
                                                          MIDh, MIDl, nullptr,
                                                          2308, 3072, 768);
        gemm_bt_k<2, 4><<<dim3(6, 19, 4), 256, 0, stream>>>(MIDh, MIDl, fc2Th, fc2Tl,
                                                            fc2_b + l * 768, X, X,
                                                            nullptr, nullptr, Kpart,
                                                            2308, 768, 3072);
        combine3_k<<<1731, 256, 0, stream>>>(X, Kpart);
    }
    final_k<<<1, 256, 0, stream>>>(X, norm_g, norm_b, (float*)d_out);
}

// Round 3
// 3112.143 us; speedup vs baseline: 1.6447x; 1.3192x over previous
//
#include <hip/hip_runtime.h>
#include <hip/hip_bf16.h>
#include <math.h>

#define BIGF 1e4f

typedef __attribute__((ext_vector_type(8))) short bf16x8;
typedef __attribute__((ext_vector_type(4))) float f32x4;

__device__ __forceinline__ unsigned short f2bf_rne(float v) {
    unsigned u = __float_as_uint(v);
    return (unsigned short)((u + 0x7FFFu + ((u >> 16) & 1u)) >> 16);
}
__device__ __forceinline__ void split_bf16(float v, unsigned short& h, unsigned short& l) {
    unsigned u = __float_as_uint(v);
    unsigned hr = (u + 0x7FFFu + ((u >> 16) & 1u)) >> 16;
    h = (unsigned short)hr;
    float hf = __uint_as_float(hr << 16);
    l = f2bf_rne(v - hf);
}

// async global->LDS, 16B per lane, wave-uniform LDS base + lane*16
__device__ __forceinline__ void gl16(const unsigned short* g, unsigned short* l) {
    __builtin_amdgcn_global_load_lds(
        (const __attribute__((address_space(1))) unsigned int*)g,
        (__attribute__((address_space(3))) unsigned int*)l, 16, 0, 0);
}

// ---------------- EDT row pass ----------------------------------------------
__global__ __launch_bounds__(64)
void edt_rows_k(const float* __restrict__ logits, const int* __restrict__ truem,
                float* __restrict__ g2o, float* __restrict__ g2z)
{
    int blk = blockIdx.x;
    int a = blk / 384, row = blk % 384;
    int lane = threadIdx.x;
    int j0 = lane * 6;
    float mk[6];
    if (a < 2) {
        const float* l0 = logits + (size_t)a * 2 * 147456 + (size_t)row * 384;
        const float* l1 = l0 + 147456;
        #pragma unroll
        for (int u = 0; u < 6; ++u) mk[u] = (l1[j0+u] > l0[j0+u]) ? 1.f : 0.f;
    } else {
        const int* t = truem + (size_t)(a - 2) * 147456 + (size_t)row * 384;
        #pragma unroll
        for (int u = 0; u < 6; ++u) mk[u] = (t[j0+u] != 0) ? 1.f : 0.f;
    }
    float lo[6], lz[6], ro[6], rz[6];
    float run_lo = -BIGF, run_lz = -BIGF;
    #pragma unroll
    for (int u = 0; u < 6; ++u) {
        float jf = (float)(j0 + u);
        if (mk[u] > 0.5f) run_lo = jf; else run_lz = jf;
        lo[u] = run_lo; lz[u] = run_lz;
    }
    float inc_o = run_lo, inc_z = run_lz;
    for (int off = 1; off < 64; off <<= 1) {
        float to = __shfl_up(inc_o, off), tz = __shfl_up(inc_z, off);
        if (lane >= off) { inc_o = fmaxf(inc_o, to); inc_z = fmaxf(inc_z, tz); }
    }
    float ex_o = __shfl_up(inc_o, 1); if (lane == 0) ex_o = -BIGF;
    float ex_z = __shfl_up(inc_z, 1); if (lane == 0) ex_z = -BIGF;

    float run_ro = BIGF, run_rz = BIGF;
    #pragma unroll
    for (int u = 5; u >= 0; --u) {
        float jf = (float)(j0 + u);
        if (mk[u] > 0.5f) run_ro = jf; else run_rz = jf;
        ro[u] = run_ro; rz[u] = run_rz;
    }
    float in2_o = run_ro, in2_z = run_rz;
    for (int off = 1; off < 64; off <<= 1) {
        float to = __shfl_down(in2_o, off), tz = __shfl_down(in2_z, off);
        if (lane + off < 64) { in2_o = fminf(in2_o, to); in2_z = fminf(in2_z, tz); }
    }
    float sx_o = __shfl_down(in2_o, 1); if (lane == 63) sx_o = BIGF;
    float sx_z = __shfl_down(in2_z, 1); if (lane == 63) sx_z = BIGF;

    size_t ob = (size_t)a * 147456 + (size_t)row * 384;
    #pragma unroll
    for (int u = 0; u < 6; ++u) {
        float jf = (float)(j0 + u);
        float dlo = jf - fmaxf(lo[u], ex_o);
        float dro = fminf(ro[u], sx_o) - jf;
        float go = fminf(fminf(dlo, dro), BIGF);
        float dlz = jf - fmaxf(lz[u], ex_z);
        float drz = fminf(rz[u], sx_z) - jf;
        float gz = fminf(fminf(dlz, drz), BIGF);
        g2o[ob + j0 + u] = go * go;
        g2z[ob + j0 + u] = gz * gz;
    }
}

// ---------------- EDT column pass -------------------------------------------
__global__ __launch_bounds__(256)
void edt_cols_k(const float* __restrict__ g2o, const float* __restrict__ g2z,
                float* __restrict__ sdm)
{
    int a = blockIdx.y;
    int w0 = blockIdx.x * 8;
    __shared__ float so[384][8];
    __shared__ float sz[384][8];
    int tid = threadIdx.x;
    for (int h = 0; h < 12; ++h) {
        int lin = tid + 256 * h;
        int ip = lin >> 3, ww = lin & 7;
        so[ip][ww] = g2o[(size_t)a * 147456 + (size_t)ip * 384 + w0 + ww];
        sz[ip][ww] = g2z[(size_t)a * 147456 + (size_t)ip * 384 + w0 + ww];
    }
    __syncthreads();
    int w = tid & 7, ib = tid >> 3;
    float vo[12], vz[12];
    #pragma unroll
    for (int r = 0; r < 12; ++r) { vo[r] = 3.4e38f; vz[r] = 3.4e38f; }
    for (int ip = 0; ip < 384; ++ip) {
        float go = so[ip][w], gz = sz[ip][w];
        #pragma unroll
        for (int r = 0; r < 12; ++r) {
            float d = (float)(ib + 32 * r - ip);
            float dd = d * d;
            vo[r] = fminf(vo[r], dd + go);
            vz[r] = fminf(vz[r], dd + gz);
        }
    }
    #pragma unroll
    for (int r = 0; r < 12; ++r) {
        sdm[(size_t)a * 147456 + (size_t)(ib + 32 * r) * 384 + w0 + w] =
            sqrtf(vo[r]) - sqrtf(vz[r]);
    }
}

// ---------------- channel-reduced patch weight ------------------------------
__global__ void weff_k(const float* __restrict__ pw, float* __restrict__ W)
{
    int i = blockIdx.x * 256 + threadIdx.x;
    if (i < 196608) W[i] = pw[i] + pw[i + 196608] + pw[i + 393216];
}

// ---------------- generic transpose + split: [K,N] f32 -> [N,K] bf16 h/l ----
__global__ __launch_bounds__(256)
void tconv_k(const float* __restrict__ src, unsigned short* __restrict__ dh,
             unsigned short* __restrict__ dl, int K, int N)
{
    __shared__ float tile[32][33];
    int t = blockIdx.x;
    int ntk = K >> 5;
    int tn = t / ntk, tk = t % ntk;
    int tid = threadIdx.x;
    int tx = tid & 31, ty = tid >> 5;
    #pragma unroll
    for (int i = 0; i < 4; ++i) {
        int k = tk * 32 + ty + i * 8;
        tile[ty + i * 8][tx] = src[(size_t)k * N + tn * 32 + tx];
    }
    __syncthreads();
    #pragma unroll
    for (int i = 0; i < 4; ++i) {
        int n = tn * 32 + ty + i * 8;
        float v = tile[tx][ty + i * 8];
        unsigned short h, l;
        split_bf16(v, h, l);
        dh[(size_t)n * K + tk * 32 + tx] = h;
        dl[(size_t)n * K + tk * 32 + tx] = l;
    }
}

// ---------------- fused per-layer weight transpose+split --------------------
__global__ __launch_bounds__(256)
void wconv_layer_k(const float* __restrict__ qkv, const float* __restrict__ proj,
                   const float* __restrict__ fc1, const float* __restrict__ fc2,
                   unsigned short* qkvTh, unsigned short* qkvTl,
                   unsigned short* projTh, unsigned short* projTl,
                   unsigned short* fc1Th, unsigned short* fc1Tl,
                   unsigned short* fc2Th, unsigned short* fc2Tl)
{
    __shared__ float tile[32][33];
    int t = blockIdx.x;
    const float* src; unsigned short *dh, *dl; int K, N, tt;
    if (t < 1728)      { src = qkv;  dh = qkvTh;  dl = qkvTl;  K = 768;  N = 2304; tt = t; }
    else if (t < 2304) { src = proj; dh = projTh; dl = projTl; K = 768;  N = 768;  tt = t - 1728; }
    else if (t < 4608) { src = fc1;  dh = fc1Th;  dl = fc1Tl;  K = 768;  N = 3072; tt = t - 2304; }
    else               { src = fc2;  dh = fc2Th;  dl = fc2Tl;  K = 3072; N = 768;  tt = t - 4608; }
    int ntk = K >> 5;
    int tn = tt / ntk, tk = tt % ntk;
    int tid = threadIdx.x;
    int tx = tid & 31, ty = tid >> 5;
    #pragma unroll
    for (int i = 0; i < 4; ++i) {
        int k = tk * 32 + ty + i * 8;
        tile[ty + i * 8][tx] = src[(size_t)k * N + tn * 32 + tx];
    }
    __syncthreads();
    #pragma unroll
    for (int i = 0; i < 4; ++i) {
        int n = tn * 32 + ty + i * 8;
        float v = tile[tx][ty + i * 8];
        unsigned short h, l;
        split_bf16(v, h, l);
        dh[(size_t)n * K + tk * 32 + tx] = h;
        dl[(size_t)n * K + tk * 32 + tx] = l;
    }
}

// ---------------- gather patch vectors, split -------------------------------
__global__ void pvec_split_k(const float* __restrict__ sdm,
                             unsigned short* __restrict__ ph,
                             unsigned short* __restrict__ pl)
{
    int idx = blockIdx.x * 256 + threadIdx.x;   // 589824 total
    int cc = idx & 15, r = (idx >> 4) & 15, p = idx >> 8;
    int px = p % 24, py = (p / 24) % 24, aa = p / 576;
    float v = sdm[(size_t)aa * 147456 + (size_t)(py * 16 + r) * 384 + px * 16 + cc];
    unsigned short h, l;
    split_bf16(v, h, l);
    ph[idx] = h; pl[idx] = l;
}

// ---------------- cls + pos assembly ---------------------------------------
__global__ void addpos_k(const float* __restrict__ tok, const float* __restrict__ cls,
                         const float* __restrict__ pos, float* __restrict__ X)
{
    int idx = blockIdx.x * 256 + threadIdx.x;
    if (idx >= 1772544) return;
    int d = idx % 768;
    int t = (idx / 768) % 577;
    int img = idx / (768 * 577);
    float v;
    if (t == 0) v = cls[d] + pos[d];
    else v = tok[((size_t)img * 576 + (t - 1)) * 768 + d] + pos[(size_t)t * 768 + d];
    X[idx] = v;
}

// ---------------- LayerNorm -> split bf16 -----------------------------------
__global__ __launch_bounds__(256)
void ln_split_k(const float* __restrict__ X, const float* __restrict__ g,
                const float* __restrict__ b, unsigned short* __restrict__ Yh,
                unsigned short* __restrict__ Yl)
{
    int row = blockIdx.x;
    const float* x = X + (size_t)row * 768;
    int tid = threadIdx.x;
    __shared__ float rs[4], rss[4];
    float v0 = x[tid], v1 = x[tid + 256], v2 = x[tid + 512];
    float s = v0 + v1 + v2;
    float ss = v0 * v0 + v1 * v1 + v2 * v2;
    for (int off = 32; off; off >>= 1) {
        s  += __shfl_xor(s, off, 64);
        ss += __shfl_xor(ss, off, 64);
    }
    if ((tid & 63) == 0) { rs[tid >> 6] = s; rss[tid >> 6] = ss; }
    __syncthreads();
    s  = rs[0] + rs[1] + rs[2] + rs[3];
    ss = rss[0] + rss[1] + rss[2] + rss[3];
    float mu  = s * (1.f / 768.f);
    float var = ss * (1.f / 768.f) - mu * mu;
    float inv = rsqrtf(var + 1e-6f);
    unsigned short h, l;
    float y0 = (v0 - mu) * inv * g[tid]       + b[tid];
    float y1 = (v1 - mu) * inv * g[tid + 256] + b[tid + 256];
    float y2 = (v2 - mu) * inv * g[tid + 512] + b[tid + 512];
    size_t base = (size_t)row * 768;
    split_bf16(y0, h, l); Yh[base + tid]       = h; Yl[base + tid]       = l;
    split_bf16(y1, h, l); Yh[base + tid + 256] = h; Yl[base + tid + 256] = l;
    split_bf16(y2, h, l); Yh[base + tid + 512] = h; Yl[base + tid + 512] = l;
}

// ---------------- split-bf16 MFMA GEMM (dbuf + optional split-K) -----------
template<int OP, int KSPLIT>
__global__ __launch_bounds__(256, 2)
void gemm_bt_k(const unsigned short* __restrict__ Ah_g, const unsigned short* __restrict__ Al_g,
               const unsigned short* __restrict__ Bh_g, const unsigned short* __restrict__ Bl_g,
               const float* __restrict__ bias, const float* __restrict__ R,
               float* __restrict__ Cf, unsigned short* __restrict__ Ch,
               unsigned short* __restrict__ Cl, float* __restrict__ Part,
               int M, int N, int K)
{
    __shared__ unsigned short LDS[2][16384];   // per buf: Ah|Al|Bh|Bl, 4096 each

    int tid = threadIdx.x;
    int lane = tid & 63, wave = tid >> 6;
    int bn = blockIdx.x * 128, bm = blockIdx.y * 128;
    int ln = lane & 15, quad = lane >> 4;
    int wm = (wave >> 1) * 64, wn = (wave & 1) * 64;

    int klen = K / KSPLIT;
    int kbeg = (KSPLIT > 1) ? blockIdx.z * klen : 0;

    int srow = wave * 32 + (lane >> 2);
    int scol = (lane & 3) * 8;
    const unsigned short* pAh = Ah_g + (size_t)(bm + srow) * K + kbeg + scol;
    const unsigned short* pAl = Al_g + (size_t)(bm + srow) * K + kbeg + scol;
    const unsigned short* pBh = Bh_g + (size_t)(bn + srow) * K + kbeg + scol;
    const unsigned short* pBl = Bl_g + (size_t)(bn + srow) * K + kbeg + scol;
    size_t rstep = (size_t)16 * K;

    f32x4 acc[4][4] = {};
    int ntiles = klen >> 5;

    {
        unsigned short* d = &LDS[0][wave * 1024];
        gl16(pAh, d);          gl16(pAh + rstep, d + 512);
        gl16(pAl, d + 4096);   gl16(pAl + rstep, d + 4608);
        gl16(pBh, d + 8192);   gl16(pBh + rstep, d + 8704);
        gl16(pBl, d + 12288);  gl16(pBl + rstep, d + 12800);
    }
    __syncthreads();

    for (int t = 0; t < ntiles; ++t) {
        if (t + 1 < ntiles) {
            int k0 = (t + 1) << 5;
            unsigned short* d = &LDS[(t + 1) & 1][wave * 1024];
            gl16(pAh + k0, d);          gl16(pAh + k0 + rstep, d + 512);
            gl16(pAl + k0, d + 4096);   gl16(pAl + k0 + rstep, d + 4608);
            gl16(pBh + k0, d + 8192);   gl16(pBh + k0 + rstep, d + 8704);
            gl16(pBl + k0, d + 12288);  gl16(pBl + k0 + rstep, d + 12800);
        }
        const unsigned short* Ah = &LDS[t & 1][0];
        const unsigned short* Al = Ah + 4096;
        const unsigned short* Bh = Ah + 8192;
        const unsigned short* Bl = Ah + 12288;

        bf16x8 fbh[4], fbl[4];
        #pragma unroll
        for (int nt = 0; nt < 4; ++nt) {
            fbh[nt] = *(const bf16x8*)&Bh[(wn + nt * 16 + ln) * 32 + quad * 8];
            fbl[nt] = *(const bf16x8*)&Bl[(wn + nt * 16 + ln) * 32 + quad * 8];
        }
        #pragma unroll
        for (int mt = 0; mt < 4; ++mt) {
            bf16x8 fah = *(const bf16x8*)&Ah[(wm + mt * 16 + ln) * 32 + quad * 8];
            bf16x8 fal = *(const bf16x8*)&Al[(wm + mt * 16 + ln) * 32 + quad * 8];
            #pragma unroll
            for (int nt = 0; nt < 4; ++nt) {
                acc[mt][nt] = __builtin_amdgcn_mfma_f32_16x16x32_bf16(fah, fbh[nt], acc[mt][nt], 0, 0, 0);
                acc[mt][nt] = __builtin_amdgcn_mfma_f32_16x16x32_bf16(fah, fbl[nt], acc[mt][nt], 0, 0, 0);
                acc[mt][nt] = __builtin_amdgcn_mfma_f32_16x16x32_bf16(fal, fbh[nt], acc[mt][nt], 0, 0, 0);
            }
        }
        __syncthreads();
    }

    if (KSPLIT > 1 && blockIdx.z > 0) {
        float* P = Part + (size_t)(blockIdx.z - 1) * ((size_t)M * N);
        #pragma unroll
        for (int mt = 0; mt < 4; ++mt) {
            #pragma unroll
            for (int i = 0; i < 4; ++i) {
                int r = bm + wm + mt * 16 + quad * 4 + i;
                if (r >= M) continue;
                #pragma unroll
                for (int nt = 0; nt < 4; ++nt) {
                    int c = bn + wn + nt * 16 + ln;
                    P[(size_t)r * N + c] = acc[mt][nt][i];
                }
            }
        }
        return;
    }
    #pragma unroll
    for (int mt = 0; mt < 4; ++mt) {
        #pragma unroll
        for (int i = 0; i < 4; ++i) {
            int r = bm + wm + mt * 16 + quad * 4 + i;
            if (r >= M) continue;
            #pragma unroll
            for (int nt = 0; nt < 4; ++nt) {
                int c = bn + wn + nt * 16 + ln;
                float v = acc[mt][nt][i] + bias[c];
                if (OP == 0) {
                    Cf[(size_t)r * N + c] = v;
                } else if (OP == 1) {
                    v = 0.5f * v * (1.f + erff(v * 0.70710678118654752f));
                    unsigned short h, l;
                    split_bf16(v, h, l);
                    Ch[(size_t)r * N + c] = h;
                    Cl[(size_t)r * N + c] = l;
                } else {
                    Cf[(size_t)r * N + c] = v + R[(size_t)r * N + c];
                }
            }
        }
    }
}

// ---------------- split-K combine: X += P0 + P1 + P2 ------------------------
__global__ __launch_bounds__(256)
void combine3_k(float* __restrict__ X, const float* __restrict__ P)
{
    int i = blockIdx.x * 256 + threadIdx.x;          // 443136 float4s total
    float4 x = ((float4*)X)[i];
    float4 a = ((const float4*)P)[i];
    float4 b = ((const float4*)P)[i + 443136];
    float4 c = ((const float4*)P)[i + 886272];
    x.x += a.x + b.x + c.x;
    x.y += a.y + b.y + c.y;
    x.z += a.z + b.z + c.z;
    x.w += a.w + b.w + c.w;
    ((float4*)X)[i] = x;
}

// ---------------- MFMA flash attention (split-bf16, vectorized staging) -----
// 4 waves/block, 16 queries/wave. K/V in 64-token tiles, float4 global loads,
// register prefetch of tile t+1 under tile t's compute (T14), XCD-aware block
// swizzle (T1) so the 10 q0-blocks sharing (img,head) K/V hit one XCD's L2.
// LDS slot swizzles: K/P rows use f(r)=r&7 (16B-slot XOR); V^T rows use
// f(d)=(d&7)^((d>>3)&7) - conflict-free for stride-8-d writes, <=2-way reads.
__global__ __launch_bounds__(256)
void attn_k(const float* __restrict__ QKV, unsigned short* __restrict__ Oh,
            unsigned short* __restrict__ Ol)
{
    const int T = 577;
    int bid = blockIdx.x + 10 * (blockIdx.y + 12 * blockIdx.z);   // 0..479
    int work = (bid & 7) * 60 + (bid >> 3);                       // T1 swizzle
    int q0   = (work % 10) * 64;
    int head = (work / 10) % 12;
    int img  = work / 120;
    const float* base = QKV + (size_t)img * T * 2304;

    __shared__ unsigned short Ksh[64 * 64], Ksl[64 * 64];   // K  [tok][d]
    __shared__ unsigned short Vth[64 * 64], Vtl[64 * 64];   // V^T [d][tok]
    __shared__ unsigned short Psh[4][16 * 64], Psl[4][16 * 64]; // per-wave P [q][tok]

    int tid = threadIdx.x;
    int wave = tid >> 6, lane = tid & 63;
    int ln = lane & 15, quad = lane >> 4;

    // ---- Q fragments: A-frag row q = ln, d = kk*32 + quad*8 (x0.125) ----
    bf16x8 qh[2], qlo[2];
    {
        int qtok = q0 + wave * 16 + ln;
        const float* qp = base + (size_t)qtok * 2304 + head * 64;
        #pragma unroll
        for (int kk = 0; kk < 2; ++kk) {
            float4 a = make_float4(0, 0, 0, 0), b = make_float4(0, 0, 0, 0);
            if (qtok < T) {
                a = *(const float4*)(qp + kk * 32 + quad * 8);
                b = *(const float4*)(qp + kk * 32 + quad * 8 + 4);
            }
            float vv[8] = {a.x, a.y, a.z, a.w, b.x, b.y, b.z, b.w};
            #pragma unroll
            for (int u = 0; u < 8; ++u) {
                unsigned short h, l;
                split_bf16(vv[u] * 0.125f, h, l);
                qh[kk][u] = (short)h; qlo[kk][u] = (short)l;
            }
        }
    }

    // staging thread mapping
    int kr  = tid >> 4;          // K: row base (16 rows per pass)
    int kd0 = (tid & 15) * 4;    // K: d offset
    int vL  = tid & 7;           // V: d block 0..7
    int vG  = tid >> 3;          // V: token-pair group 0..31
    int vd0 = vL * 8;
    int vt0 = vG * 2;

    float4 kf[4];                // prefetched K rows
    float4 vf[4];                // prefetched V (2 tok x 8 d)

    float m[4], lsum[4];
    f32x4 acc_o[4] = {};
    #pragma unroll
    for (int i = 0; i < 4; ++i) { m[i] = -1e30f; lsum[i] = 0.f; }

    // prologue: load tile 0 into registers
    {
        #pragma unroll
        for (int p = 0; p < 4; ++p) {
            int r = p * 16 + kr;
            kf[p] = make_float4(0, 0, 0, 0);
            if (r < T) kf[p] = *(const float4*)(base + (size_t)r * 2304 + 768 + head * 64 + kd0);
        }
        const float* vp = base + (size_t)vt0 * 2304 + 1536 + head * 64 + vd0;
        vf[0] = *(const float4*)(vp);
        vf[1] = *(const float4*)(vp + 4);
        vf[2] = *(const float4*)(vp + 2304);
        vf[3] = *(const float4*)(vp + 2308);
    }

    for (int t = 0; t < 10; ++t) {
        int c0 = t * 64;
        // ---- write staged registers -> LDS ----
        #pragma unroll
        for (int p = 0; p < 4; ++p) {
            int r = p * 16 + kr;
            float vv[4] = {kf[p].x, kf[p].y, kf[p].z, kf[p].w};
            ushort4 hh, ll;
            unsigned short h, l;
            split_bf16(vv[0], h, l); hh.x = h; ll.x = l;
            split_bf16(vv[1], h, l); hh.y = h; ll.y = l;
            split_bf16(vv[2], h, l); hh.z = h; ll.z = l;
            split_bf16(vv[3], h, l); hh.w = h; ll.w = l;
            int e = (r * 64 + kd0) ^ ((r & 7) << 3);
            *(ushort4*)&Ksh[e] = hh;
            *(ushort4*)&Ksl[e] = ll;
        }
        {
            float va[8] = {vf[0].x, vf[0].y, vf[0].z, vf[0].w,
                           vf[1].x, vf[1].y, vf[1].z, vf[1].w};
            float vb[8] = {vf[2].x, vf[2].y, vf[2].z, vf[2].w,
                           vf[3].x, vf[3].y, vf[3].z, vf[3].w};
            #pragma unroll
            for (int j = 0; j < 8; ++j) {
                int d = vd0 + j;
                unsigned short ha, la, hb, lb;
                split_bf16(va[j], ha, la);
                split_bf16(vb[j], hb, lb);
                int e = (d * 64 + vt0) ^ (((d & 7) ^ ((d >> 3) & 7)) << 3);
                *(unsigned*)&Vth[e] = (unsigned)ha | ((unsigned)hb << 16);
                *(unsigned*)&Vtl[e] = (unsigned)la | ((unsigned)lb << 16);
            }
        }
        __syncthreads();

        // ---- prefetch tile t+1 into registers (overlaps compute) ----
        if (t < 9) {
            int cn = c0 + 64;
            #pragma unroll
            for (int p = 0; p < 4; ++p) {
                int r = p * 16 + kr;
                kf[p] = make_float4(0, 0, 0, 0);
                if (cn + r < T) kf[p] = *(const float4*)(base + (size_t)(cn + r) * 2304 + 768 + head * 64 + kd0);
            }
            const float* vp = base + (size_t)(cn + vt0) * 2304 + 1536 + head * 64 + vd0;
            bool ok0 = (cn + vt0) < T, ok1 = (cn + vt0 + 1) < T;
            vf[0] = ok0 ? *(const float4*)(vp)        : make_float4(0, 0, 0, 0);
            vf[1] = ok0 ? *(const float4*)(vp + 4)    : make_float4(0, 0, 0, 0);
            vf[2] = ok1 ? *(const float4*)(vp + 2304) : make_float4(0, 0, 0, 0);
            vf[3] = ok1 ? *(const float4*)(vp + 2308) : make_float4(0, 0, 0, 0);
        }

        // ---- S = Q K^T (split 3-term) ----
        f32x4 s4[4] = {};
        #pragma unroll
        for (int nt = 0; nt < 4; ++nt) {
            int row = nt * 16 + ln;
            #pragma unroll
            for (int kk = 0; kk < 2; ++kk) {
                int e = (row * 64 + kk * 32 + quad * 8) ^ ((row & 7) << 3);
                bf16x8 kbh = *(const bf16x8*)&Ksh[e];
                bf16x8 kbl = *(const bf16x8*)&Ksl[e];
                s4[nt] = __builtin_amdgcn_mfma_f32_16x16x32_bf16(qh[kk],  kbh, s4[nt], 0, 0, 0);
                s4[nt] = __builtin_amdgcn_mfma_f32_16x16x32_bf16(qh[kk],  kbl, s4[nt], 0, 0, 0);
                s4[nt] = __builtin_amdgcn_mfma_f32_16x16x32_bf16(qlo[kk], kbh, s4[nt], 0, 0, 0);
            }
        }

        // ---- online softmax ----
        bool full = (c0 + 64 <= T);
        float p[4][4];
        #pragma unroll
        for (int i = 0; i < 4; ++i) {
            float mx = -1e30f;
            #pragma unroll
            for (int nt = 0; nt < 4; ++nt) {
                float sv = s4[nt][i];
                if (!full && (c0 + nt * 16 + ln >= T)) sv = -1e30f;
                p[nt][i] = sv;
                mx = fmaxf(mx, sv);
            }
            mx = fmaxf(mx, __shfl_xor(mx, 1));
            mx = fmaxf(mx, __shfl_xor(mx, 2));
            mx = fmaxf(mx, __shfl_xor(mx, 4));
            mx = fmaxf(mx, __shfl_xor(mx, 8));
            float mnew = fmaxf(m[i], mx);
            float alpha = __expf(m[i] - mnew);
            m[i] = mnew;
            float rsum = 0.f;
            #pragma unroll
            for (int nt = 0; nt < 4; ++nt) {
                float pv = __expf(p[nt][i] - mnew);
                p[nt][i] = pv;
                rsum += pv;
            }
            rsum += __shfl_xor(rsum, 1); rsum += __shfl_xor(rsum, 2);
            rsum += __shfl_xor(rsum, 4); rsum += __shfl_xor(rsum, 8);
            lsum[i] = lsum[i] * alpha + rsum;
            acc_o[0][i] *= alpha; acc_o[1][i] *= alpha;
            acc_o[2][i] *= alpha; acc_o[3][i] *= alpha;
        }

        // ---- P -> split bf16 into per-wave LDS tile (direct u16 writes) ----
        unsigned short* php = Psh[wave];
        unsigned short* plp = Psl[wave];
        #pragma unroll
        for (int i = 0; i < 4; ++i) {
            int row = quad * 4 + i;
            #pragma unroll
            for (int nt = 0; nt < 4; ++nt) {
                unsigned short h, l;
                split_bf16(p[nt][i], h, l);
                int e = (row * 64 + nt * 16 + ln) ^ ((row & 7) << 3);
                php[e] = h;
                plp[e] = l;
            }
        }

        // ---- O += P V ----
        #pragma unroll
        for (int kk = 0; kk < 2; ++kk) {
            int ea = (ln * 64 + kk * 32 + quad * 8) ^ ((ln & 7) << 3);
            bf16x8 pah = *(const bf16x8*)&php[ea];
            bf16x8 pal = *(const bf16x8*)&plp[ea];
            #pragma unroll
            for (int nt = 0; nt < 4; ++nt) {
                int row = nt * 16 + ln;
                int eb = (row * 64 + kk * 32 + quad * 8) ^ (((row & 7) ^ ((row >> 3) & 7)) << 3);
                bf16x8 vbh = *(const bf16x8*)&Vth[eb];
                bf16x8 vbl = *(const bf16x8*)&Vtl[eb];
                acc_o[nt] = __builtin_amdgcn_mfma_f32_16x16x32_bf16(pah, vbh, acc_o[nt], 0, 0, 0);
                acc_o[nt] = __builtin_amdgcn_mfma_f32_16x16x32_bf16(pah, vbl, acc_o[nt], 0, 0, 0);
                acc_o[nt] = __builtin_amdgcn_mfma_f32_16x16x32_bf16(pal, vbh, acc_o[nt], 0, 0, 0);
            }
        }
        __syncthreads();
    }

    // ---- epilogue: O row = quad*4+i, col = nt*16+ln ----
    #pragma unroll
    for (int i = 0; i < 4; ++i) {
        int tok = q0 + wave * 16 + quad * 4 + i;
        if (tok >= T) continue;
        float inv = 1.f / lsum[i];
        size_t rowb = (size_t)(img * 577 + tok) * 768 + head * 64;
        #pragma unroll
        for (int nt = 0; nt < 4; ++nt) {
            unsigned short h, l;
            split_bf16(acc_o[nt][i] * inv, h, l);
            Oh[rowb + nt * 16 + ln] = h;
            Ol[rowb + nt * 16 + ln] = l;
        }
    }
}

// ---------------- final LN(cls) + cosine loss -------------------------------
__global__ __launch_bounds__(256)
void final_k(const float* __restrict__ X, const float* __restrict__ g,
             const float* __restrict__ b, float* __restrict__ out)
{
    __shared__ float F[4][768];
    __shared__ float rs[4], rss[4];
    __shared__ float rd[4], rna[4], rnb[4];
    __shared__ float cosv[2];
    int tid = threadIdx.x;
    for (int rr = 0; rr < 4; ++rr) {
        const float* x = X + (size_t)rr * 577 * 768;
        float v0 = x[tid], v1 = x[tid + 256], v2 = x[tid + 512];
        float s = v0 + v1 + v2;
        float ss = v0 * v0 + v1 * v1 + v2 * v2;
        for (int off = 32; off; off >>= 1) {
            s  += __shfl_xor(s, off, 64);
            ss += __shfl_xor(ss, off, 64);
        }
        if ((tid & 63) == 0) { rs[tid >> 6] = s; rss[tid >> 6] = ss; }
        __syncthreads();
        s  = rs[0] + rs[1] + rs[2] + rs[3];
        ss = rss[0] + rss[1] + rss[2] + rss[3];
        float mu  = s * (1.f / 768.f);
        float var = ss * (1.f / 768.f) - mu * mu;
        float inv = rsqrtf(var + 1e-6f);
        F[rr][tid]       = (v0 - mu) * inv * g[tid]       + b[tid];
        F[rr][tid + 256] = (v1 - mu) * inv * g[tid + 256] + b[tid + 256];
        F[rr][tid + 512] = (v2 - mu) * inv * g[tid + 512] + b[tid + 512];
        __syncthreads();
    }
    for (int bb = 0; bb < 2; ++bb) {
        float d = 0.f, na = 0.f, nb = 0.f;
        for (int u = tid; u < 768; u += 256) {
            float fa = F[bb][u], fb = F[bb + 2][u];
            d += fa * fb; na += fa * fa; nb += fb * fb;
        }
        for (int off = 32; off; off >>= 1) {
            d  += __shfl_xor(d, off, 64);
            na += __shfl_xor(na, off, 64);
            nb += __shfl_xor(nb, off, 64);
        }
        if ((tid & 63) == 0) { rd[tid >> 6] = d; rna[tid >> 6] = na; rnb[tid >> 6] = nb; }
        __syncthreads();
        if (tid == 0) {
            float D  = rd[0] + rd[1] + rd[2] + rd[3];
            float NA = sqrtf(rna[0] + rna[1] + rna[2] + rna[3]);
            float NB = sqrtf(rnb[0] + rnb[1] + rnb[2] + rnb[3]);
            cosv[bb] = D / (fmaxf(NA, 1e-8f) * fmaxf(NB, 1e-8f));
        }
        __syncthreads();
    }
    if (tid == 0) out[0] = 1.f - 0.5f * (cosv[0] + cosv[1]);
}

// ---------------- host orchestration ----------------------------------------
extern "C" void kernel_launch(void* const* d_in, const int* in_sizes, int n_in,
                              void* d_out, int out_size, void* d_ws, size_t ws_size,
                              hipStream_t stream)
{
    const float* logits  = (const float*)d_in[0];
    const int*   truem   = (const int*)d_in[1];
    const float* patch_w = (const float*)d_in[2];
    const float* patch_b = (const float*)d_in[3];
    const float* cls_tok = (const float*)d_in[4];
    const float* pos_emb = (const float*)d_in[5];
    const float* ln1_g   = (const float*)d_in[6];
    const float* ln1_b   = (const float*)d_in[7];
    const float* qkv_w   = (const float*)d_in[8];
    const float* qkv_b   = (const float*)d_in[9];
    const float* proj_w  = (const float*)d_in[10];
    const float* proj_b  = (const float*)d_in[11];
    const float* ln2_g   = (const float*)d_in[12];
    const float* ln2_b   = (const float*)d_in[13];
    const float* fc1_w   = (const float*)d_in[14];
    const float* fc1_b   = (const float*)d_in[15];
    const float* fc2_w   = (const float*)d_in[16];
    const float* fc2_b   = (const float*)d_in[17];
    const float* norm_g  = (const float*)d_in[18];
    const float* norm_b  = (const float*)d_in[19];

    char* p = (char*)d_ws;
    float* X             = (float*)(p + 0);              //  7,090,176 B (2308x768 f32)
    float* QKV           = (float*)(p + 7090176);        // 21,270,528 B (2308x2304 f32)
    unsigned short* qkvTh = (unsigned short*)(p + 28360704);  // 2304x768
    unsigned short* qkvTl = (unsigned short*)(p + 31899648);
    unsigned short* projTh= (unsigned short*)(p + 35438592);  // 768x768
    unsigned short* projTl= (unsigned short*)(p + 36618240);
    unsigned short* fc1Th = (unsigned short*)(p + 37797888);  // 3072x768
    unsigned short* fc1Tl = (unsigned short*)(p + 42516480);
    unsigned short* fc2Th = (unsigned short*)(p + 47235072);  // 768x3072
    unsigned short* fc2Tl = (unsigned short*)(p + 51953664);
    unsigned short* Hh    = (unsigned short*)(p + 56672256);  // 2432x768
    unsigned short* Hl    = (unsigned short*)(p + 60407808);
    unsigned short* Oh    = (unsigned short*)(p + 64143360);  // 2432x768
    unsigned short* Ol    = (unsigned short*)(p + 67878912);
    unsigned short* MIDh  = (unsigned short*)(p + 71614464);  // 2432x3072
    unsigned short* MIDl  = (unsigned short*)(p + 86556672);
    // EDT/patch phase overlays (dead before layer loop uses the regions):
    float* g2o   = (float*)MIDh;
    float* g2z   = g2o + 589824;
    float* sdm   = (float*)MIDl;
    unsigned short* pvh = Hh;
    unsigned short* pvl = Hl;
    float* Weff  = (float*)Oh;           // 256x768 f32
    unsigned short* WeffTh = qkvTh;      // 768x256
    unsigned short* WeffTl = qkvTl;
    float* tokb  = QKV;                  // 2304x768 f32
    float* Kpart = QKV;                  // split-K partials (3x 2308x768 f32 = QKV region)

    edt_rows_k<<<1536, 64, 0, stream>>>(logits, truem, g2o, g2z);
    edt_cols_k<<<dim3(48, 4), 256, 0, stream>>>(g2o, g2z, sdm);
    weff_k<<<768, 256, 0, stream>>>(patch_w, Weff);
    tconv_k<<<192, 256, 0, stream>>>(Weff, WeffTh, WeffTl, 256, 768);
    pvec_split_k<<<2304, 256, 0, stream>>>(sdm, pvh, pvl);
    gemm_bt_k<0, 1><<<dim3(6, 18), 256, 0, stream>>>(pvh, pvl, WeffTh, WeffTl, patch_b,
                                                     nullptr, tokb, nullptr, nullptr,
                                                     nullptr, 2304, 768, 256);
    addpos_k<<<6924, 256, 0, stream>>>(tokb, cls_tok, pos_emb, X);

    for (int l = 0; l < 12; ++l) {
        wconv_layer_k<<<6912, 256, 0, stream>>>(
            qkv_w + (size_t)l * 768 * 2304, proj_w + (size_t)l * 768 * 768,
            fc1_w + (size_t)l * 768 * 3072, fc2_w + (size_t)l * 3072 * 768,
            qkvTh, qkvTl, projTh, projTl, fc1Th, fc1Tl, fc2Th, fc2Tl);
        ln_split_k<<<2308, 256, 0, stream>>>(X, ln1_g + l * 768, ln1_b + l * 768, Hh, Hl);
        gemm_bt_k<0, 1><<<dim3(18, 19), 256, 0, stream>>>(Hh, Hl, qkvTh, qkvTl,
                                                          qkv_b + l * 2304, nullptr, QKV,
                                                          nullptr, nullptr, nullptr,
                                                          2308, 2304, 768);
        attn_k<<<dim3(10, 12, 4), 256, 0, stream>>>(QKV, Oh, Ol);
        gemm_bt_k<2, 4><<<dim3(6, 19, 4), 256, 0, stream>>>(Oh, Ol, projTh, projTl,
                                                            proj_b + l * 768, X, X,
                                                            nullptr, nullptr, Kpart,
                                                            2308, 768, 768);
        combine3_k<<<1731, 256, 0, stream>>>(X, Kpart);
        ln_split_k<<<2308, 256, 0, stream>>>(X, ln2_g + l * 768, ln2_b + l * 768, Hh, Hl);
        gemm_bt_k<1, 1><<<dim3(24, 19), 256, 0, stream>>>(Hh, Hl, fc1Th, fc1Tl,
                                                          fc1_b + l * 3072, nullptr, nullptr,
                                                          MIDh, MIDl, nullptr,
                                                          2308, 3072, 768);
        gemm_bt_k<2, 4><<<dim3(6, 19, 4), 256, 0, stream>>>(MIDh, MIDl, fc2Th, fc2Tl,
                                                            fc2_b + l * 768, X, X,
                                                            nullptr, nullptr, Kpart,
                                                            2308, 768, 3072);
        combine3_k<<<1731, 256, 0, stream>>>(X, Kpart);
    }
    final_k<<<1, 256, 0, stream>>>(X, norm_g, norm_b, (float*)d_out);
}